// Round 1
// baseline (1235.931 us; speedup 1.0000x reference)
//
#include <hip/hip_runtime.h>
#include <cstddef>
#include <cstdint>

#define NB 2
#define L_SEQ 2048
#define DM 512
#define DS 16
#define DI 1024

__device__ __forceinline__ float softplus_f(float x) {
  return (x > 20.f) ? x : log1pf(expf(x));
}
__device__ __forceinline__ float silu_f(float x) {
  return x / (1.f + expf(-x));
}

// C[M,N] = A[M,K] @ B[N,K]^T  (+ bias, + softplus) ; all dims multiple of tile
// ACT: 0 = none, 1 = softplus(x + bias)
template <int ACT>
__global__ __launch_bounds__(256) void gemm_nt(
    const float* __restrict__ A, int lda,
    const float* __restrict__ B, int ldb,
    const float* __restrict__ bias,
    float* __restrict__ C, int ldc,
    int M, int N, int K) {
  constexpr int BM = 64, BN = 64, BK = 16;
  __shared__ float As[BK][BM + 4];
  __shared__ float Bs[BK][BN + 4];
  const int tid = threadIdx.x;
  const int m0 = blockIdx.y * BM;
  const int n0 = blockIdx.x * BN;
  const int lr = tid >> 2;   // 0..63 row within tile for loading
  const int kq = tid & 3;    // which float4 along k
  const float* Ap = A + (size_t)(m0 + lr) * lda + kq * 4;
  const float* Bp = B + (size_t)(n0 + lr) * ldb + kq * 4;
  const int tx = tid & 15, ty = tid >> 4;

  float acc[4][4];
#pragma unroll
  for (int i = 0; i < 4; i++)
#pragma unroll
    for (int j = 0; j < 4; j++) acc[i][j] = 0.f;

  for (int k0 = 0; k0 < K; k0 += BK) {
    float4 av = *(const float4*)(Ap + k0);
    float4 bv = *(const float4*)(Bp + k0);
    __syncthreads();
    As[kq * 4 + 0][lr] = av.x;
    As[kq * 4 + 1][lr] = av.y;
    As[kq * 4 + 2][lr] = av.z;
    As[kq * 4 + 3][lr] = av.w;
    Bs[kq * 4 + 0][lr] = bv.x;
    Bs[kq * 4 + 1][lr] = bv.y;
    Bs[kq * 4 + 2][lr] = bv.z;
    Bs[kq * 4 + 3][lr] = bv.w;
    __syncthreads();
#pragma unroll
    for (int k = 0; k < BK; k++) {
      float4 a = *(const float4*)&As[k][ty * 4];
      float4 b = *(const float4*)&Bs[k][tx * 4];
      acc[0][0] += a.x * b.x; acc[0][1] += a.x * b.y; acc[0][2] += a.x * b.z; acc[0][3] += a.x * b.w;
      acc[1][0] += a.y * b.x; acc[1][1] += a.y * b.y; acc[1][2] += a.y * b.z; acc[1][3] += a.y * b.w;
      acc[2][0] += a.z * b.x; acc[2][1] += a.z * b.y; acc[2][2] += a.z * b.z; acc[2][3] += a.z * b.w;
      acc[3][0] += a.w * b.x; acc[3][1] += a.w * b.y; acc[3][2] += a.w * b.z; acc[3][3] += a.w * b.w;
    }
  }

#pragma unroll
  for (int i = 0; i < 4; i++) {
    float4 v = make_float4(acc[i][0], acc[i][1], acc[i][2], acc[i][3]);
    if (ACT == 1) {
      const int col = n0 + tx * 4;
      v.x = softplus_f(v.x + bias[col + 0]);
      v.y = softplus_f(v.y + bias[col + 1]);
      v.z = softplus_f(v.z + bias[col + 2]);
      v.w = softplus_f(v.w + bias[col + 3]);
    }
    *(float4*)(C + (size_t)(m0 + ty * 4 + i) * ldc + n0 + tx * 4) = v;
  }
}

// depthwise causal conv (k=4, left pad 3) + SiLU.  xz layout [rows][2048], xi = cols 0..1023
__global__ __launch_bounds__(256) void conv_silu_kernel(
    const float* __restrict__ xz, const float* __restrict__ conv_w,
    const float* __restrict__ conv_b, float* __restrict__ h) {
  const int idx = blockIdx.x * 256 + threadIdx.x;  // rows*1024
  const int c = idx & (DI - 1);
  const int r = idx >> 10;
  const int l = r & (L_SEQ - 1);
  const float w0 = conv_w[c * 4 + 0];
  const float w1 = conv_w[c * 4 + 1];
  const float w2 = conv_w[c * 4 + 2];
  const float w3 = conv_w[c * 4 + 3];
  const float* xp = xz + (size_t)r * (2 * DI) + c;
  float acc = conv_b[c];
  if (l >= 3) acc += xp[-3 * 2 * DI] * w0;
  if (l >= 2) acc += xp[-2 * 2 * DI] * w1;
  if (l >= 1) acc += xp[-1 * 2 * DI] * w2;
  acc += xp[0] * w3;
  h[idx] = silu_f(acc);
}

// Bmat[r][s] = dot(h[r][:], W_x[16+s][:])
__global__ __launch_bounds__(256) void xproj_kernel(
    const float* __restrict__ h, const float* __restrict__ W_x,
    float* __restrict__ Bm) {
  const int idx = blockIdx.x * 256 + threadIdx.x;  // rows*16
  const int s = idx & 15;
  const int r = idx >> 4;
  const float* hp = h + (size_t)r * DI;
  const float* wp = W_x + (size_t)(DS + s) * DI;
  float acc = 0.f;
  for (int k = 0; k < DI; k += 4) {
    float4 hv = *(const float4*)(hp + k);
    float4 wv = *(const float4*)(wp + k);
    acc += hv.x * wv.x + hv.y * wv.y + hv.z * wv.z + hv.w * wv.w;
  }
  Bm[idx] = acc;
}

// selective scan: one thread per (b, c, s); 16-lane shuffle reduce for y
__global__ __launch_bounds__(64) void scan_kernel(
    const float* __restrict__ delta, const float* __restrict__ h,
    const float* __restrict__ Bm, const float* __restrict__ A_log,
    float* __restrict__ y) {
  const int tid = threadIdx.x;      // 64
  const int s = tid & 15;
  const int cl = tid >> 4;          // 0..3
  const int b = blockIdx.x >> 8;    // DI/4 = 256 groups per batch
  const int cg = blockIdx.x & 255;
  const int c = cg * 4 + cl;
  const float Acs = -__expf(A_log[c * DS + s]);
  const float* dp = delta + (size_t)b * L_SEQ * DI + c;
  const float* hp = h + (size_t)b * L_SEQ * DI + c;
  const float* Bp = Bm + (size_t)b * L_SEQ * DS + s;
  float* yp = y + (size_t)b * L_SEQ * DI + c;
  float state = 0.f;
  for (int t = 0; t < L_SEQ; ++t) {
    const float dt = dp[(size_t)t * DI];
    const float ht = hp[(size_t)t * DI];
    const float bt = Bp[(size_t)t * DS];
    const float da = __expf(dt * Acs);
    state = da * state + dt * bt * ht;
    float yv = state * bt;
    yv += __shfl_xor(yv, 1);
    yv += __shfl_xor(yv, 2);
    yv += __shfl_xor(yv, 4);
    yv += __shfl_xor(yv, 8);
    if (s == 0) yp[(size_t)t * DI] = yv;
  }
}

// y2 = (y + D*h) * silu(z)   (in place on y)
__global__ __launch_bounds__(256) void gate_kernel(
    float* __restrict__ y, const float* __restrict__ h,
    const float* __restrict__ xz, const float* __restrict__ Dp) {
  const int idx = blockIdx.x * 256 + threadIdx.x;  // rows*1024
  const int c = idx & (DI - 1);
  const int r = idx >> 10;
  const float z = xz[(size_t)r * (2 * DI) + DI + c];
  y[idx] = (y[idx] + Dp[c] * h[idx]) * silu_f(z);
}

extern "C" void kernel_launch(void* const* d_in, const int* in_sizes, int n_in,
                              void* d_out, int out_size, void* d_ws, size_t ws_size,
                              hipStream_t stream) {
  const float* x      = (const float*)d_in[0];
  const float* W_in   = (const float*)d_in[1];
  const float* conv_w = (const float*)d_in[2];
  const float* conv_b = (const float*)d_in[3];
  const float* W_x    = (const float*)d_in[4];
  const float* W_dt   = (const float*)d_in[5];
  const float* b_dt   = (const float*)d_in[6];
  const float* A_log  = (const float*)d_in[7];
  const float* D_par  = (const float*)d_in[8];
  const float* W_out  = (const float*)d_in[9];
  float* out = (float*)d_out;

  const int rows = NB * L_SEQ;  // 4096

  float* xz    = (float*)d_ws;                        // rows * 2048
  float* h     = xz + (size_t)rows * (2 * DI);        // rows * 1024
  float* delta = h + (size_t)rows * DI;               // rows * 1024
  float* yb    = delta + (size_t)rows * DI;           // rows * 1024
  float* Bm    = yb + (size_t)rows * DI;              // rows * 16

  // 1) xz = x @ W_in^T   [4096,512]x[512,2048]
  gemm_nt<0><<<dim3((2 * DI) / 64, rows / 64), 256, 0, stream>>>(
      x, DM, W_in, DM, nullptr, xz, 2 * DI, rows, 2 * DI, DM);
  // 2) depthwise conv + silu -> h
  conv_silu_kernel<<<(rows * DI) / 256, 256, 0, stream>>>(xz, conv_w, conv_b, h);
  // 3) delta = softplus(h @ W_dt^T + b_dt)
  gemm_nt<1><<<dim3(DI / 64, rows / 64), 256, 0, stream>>>(
      h, DI, W_dt, DI, b_dt, delta, DI, rows, DI, DI);
  // 3b) Bmat = h @ W_x[16:32]^T
  xproj_kernel<<<(rows * DS) / 256, 256, 0, stream>>>(h, W_x, Bm);
  // 4) selective scan -> yb
  scan_kernel<<<NB * (DI / 4), 64, 0, stream>>>(delta, h, Bm, A_log, yb);
  // 5) gate: yb = (yb + D*h) * silu(z)
  gate_kernel<<<(rows * DI) / 256, 256, 0, stream>>>(yb, h, xz, D_par);
  // 6) out = yb @ W_out^T   [4096,1024]x[1024,512]
  gemm_nt<0><<<dim3(DM / 64, rows / 64), 256, 0, stream>>>(
      yb, DI, W_out, DI, nullptr, out, DM, rows, DM, DI);
}

// Round 2
// 526.100 us; speedup vs baseline: 2.3492x; 2.3492x over previous
//
#include <hip/hip_runtime.h>
#include <cstddef>
#include <cstdint>

#define NB 2
#define L_SEQ 2048
#define DM 512
#define DS 16
#define DI 1024
#define NC 16          // chunks along L
#define CL (L_SEQ/NC)  // 128

__device__ __forceinline__ float softplus_f(float x) {
  return (x > 20.f) ? x : log1pf(expf(x));
}
__device__ __forceinline__ float silu_f(float x) {
  return x / (1.f + expf(-x));
}

// C[M,N] = A[M,K] @ B[N,K]^T  (+ bias, + softplus)
template <int ACT>
__global__ __launch_bounds__(256) void gemm_nt(
    const float* __restrict__ A, int lda,
    const float* __restrict__ B, int ldb,
    const float* __restrict__ bias,
    float* __restrict__ C, int ldc,
    int M, int N, int K) {
  constexpr int BM = 64, BN = 64, BK = 16;
  __shared__ float As[BK][BM + 4];
  __shared__ float Bs[BK][BN + 4];
  const int tid = threadIdx.x;
  const int m0 = blockIdx.y * BM;
  const int n0 = blockIdx.x * BN;
  const int lr = tid >> 2;
  const int kq = tid & 3;
  const float* Ap = A + (size_t)(m0 + lr) * lda + kq * 4;
  const float* Bp = B + (size_t)(n0 + lr) * ldb + kq * 4;
  const int tx = tid & 15, ty = tid >> 4;

  float acc[4][4];
#pragma unroll
  for (int i = 0; i < 4; i++)
#pragma unroll
    for (int j = 0; j < 4; j++) acc[i][j] = 0.f;

  for (int k0 = 0; k0 < K; k0 += BK) {
    float4 av = *(const float4*)(Ap + k0);
    float4 bv = *(const float4*)(Bp + k0);
    __syncthreads();
    As[kq * 4 + 0][lr] = av.x;
    As[kq * 4 + 1][lr] = av.y;
    As[kq * 4 + 2][lr] = av.z;
    As[kq * 4 + 3][lr] = av.w;
    Bs[kq * 4 + 0][lr] = bv.x;
    Bs[kq * 4 + 1][lr] = bv.y;
    Bs[kq * 4 + 2][lr] = bv.z;
    Bs[kq * 4 + 3][lr] = bv.w;
    __syncthreads();
#pragma unroll
    for (int k = 0; k < BK; k++) {
      float4 a = *(const float4*)&As[k][ty * 4];
      float4 b = *(const float4*)&Bs[k][tx * 4];
      acc[0][0] += a.x * b.x; acc[0][1] += a.x * b.y; acc[0][2] += a.x * b.z; acc[0][3] += a.x * b.w;
      acc[1][0] += a.y * b.x; acc[1][1] += a.y * b.y; acc[1][2] += a.y * b.z; acc[1][3] += a.y * b.w;
      acc[2][0] += a.z * b.x; acc[2][1] += a.z * b.y; acc[2][2] += a.z * b.z; acc[2][3] += a.z * b.w;
      acc[3][0] += a.w * b.x; acc[3][1] += a.w * b.y; acc[3][2] += a.w * b.z; acc[3][3] += a.w * b.w;
    }
  }

#pragma unroll
  for (int i = 0; i < 4; i++) {
    float4 v = make_float4(acc[i][0], acc[i][1], acc[i][2], acc[i][3]);
    if (ACT == 1) {
      const int col = n0 + tx * 4;
      v.x = softplus_f(v.x + bias[col + 0]);
      v.y = softplus_f(v.y + bias[col + 1]);
      v.z = softplus_f(v.z + bias[col + 2]);
      v.w = softplus_f(v.w + bias[col + 3]);
    }
    *(float4*)(C + (size_t)(m0 + ty * 4 + i) * ldc + n0 + tx * 4) = v;
  }
}

// depthwise causal conv (k=4) + SiLU
__global__ __launch_bounds__(256) void conv_silu_kernel(
    const float* __restrict__ xz, const float* __restrict__ conv_w,
    const float* __restrict__ conv_b, float* __restrict__ h) {
  const int idx = blockIdx.x * 256 + threadIdx.x;
  const int c = idx & (DI - 1);
  const int r = idx >> 10;
  const int l = r & (L_SEQ - 1);
  const float w0 = conv_w[c * 4 + 0];
  const float w1 = conv_w[c * 4 + 1];
  const float w2 = conv_w[c * 4 + 2];
  const float w3 = conv_w[c * 4 + 3];
  const float* xp = xz + (size_t)r * (2 * DI) + c;
  float acc = conv_b[c];
  if (l >= 3) acc += xp[-3 * 2 * DI] * w0;
  if (l >= 2) acc += xp[-2 * 2 * DI] * w1;
  if (l >= 1) acc += xp[-1 * 2 * DI] * w2;
  acc += xp[0] * w3;
  h[idx] = silu_f(acc);
}

// Bmat[r][s] = dot(h[r][:], W_x[16+s][:])
__global__ __launch_bounds__(256) void xproj_kernel(
    const float* __restrict__ h, const float* __restrict__ W_x,
    float* __restrict__ Bm) {
  const int idx = blockIdx.x * 256 + threadIdx.x;
  const int s = idx & 15;
  const int r = idx >> 4;
  const float* hp = h + (size_t)r * DI;
  const float* wp = W_x + (size_t)(DS + s) * DI;
  float acc = 0.f;
  for (int k = 0; k < DI; k += 4) {
    float4 hv = *(const float4*)(hp + k);
    float4 wv = *(const float4*)(wp + k);
    acc += hv.x * wv.x + hv.y * wv.y + hv.z * wv.z + hv.w * wv.w;
  }
  Bm[idx] = acc;
}

// ---- chunked selective scan ----
// lane layout per block (256 thr): s = tid&15, channel = tid>>4 (16 ch/block)
// grid: b(2) x chunk(16) x cgroup(64)

__global__ __launch_bounds__(256) void scan_phase1(
    const float* __restrict__ delta, const float* __restrict__ h,
    const float* __restrict__ Bm, const float* __restrict__ A_log,
    float* __restrict__ aprod, float* __restrict__ blocal) {
  const int tid = threadIdx.x;
  const int s = tid & 15;
  const int cl = tid >> 4;            // 0..15
  const int blk = blockIdx.x;         // 2048
  const int cg = blk & 63;
  const int chunk = (blk >> 6) & 15;
  const int b = blk >> 10;
  const int c = cg * 16 + cl;
  const float Acs = -__expf(A_log[c * DS + s]);
  const int t0 = chunk * CL;
  const float* dp = delta + ((size_t)b * L_SEQ + t0) * DI + c;
  const float* hp = h + ((size_t)b * L_SEQ + t0) * DI + c;
  const float* Bp = Bm + ((size_t)b * L_SEQ + t0) * DS + s;
  float state = 0.f, sdt = 0.f;
  for (int t = 0; t < CL; ++t) {
    const float dt = dp[(size_t)t * DI];
    const float ht = hp[(size_t)t * DI];
    const float bt = Bp[(size_t)t * DS];
    sdt += dt;
    state = __expf(dt * Acs) * state + dt * bt * ht;
  }
  const size_t o = (((size_t)b * NC + chunk) * DI + c) * DS + s;
  aprod[o] = __expf(Acs * sdt);
  blocal[o] = state;
}

__global__ __launch_bounds__(256) void scan_phase2(
    const float* __restrict__ aprod, const float* __restrict__ blocal,
    float* __restrict__ sinit) {
  const int idx = blockIdx.x * 256 + threadIdx.x;  // NB*DI*DS = 32768
  const int b = idx >> 14;
  const int cs = idx & 16383;
  float st = 0.f;
  for (int ch = 0; ch < NC; ++ch) {
    const size_t o = (size_t)(b * NC + ch) * (DI * DS) + cs;
    const float a = aprod[o];
    const float bl = blocal[o];
    sinit[o] = st;
    st = a * st + bl;
  }
}

// phase 3: rerun chunk with proper init; fused gate: y = (y + D*h)*silu(z)
__global__ __launch_bounds__(256) void scan_phase3(
    const float* __restrict__ delta, const float* __restrict__ h,
    const float* __restrict__ Bm, const float* __restrict__ A_log,
    const float* __restrict__ sinit, const float* __restrict__ xz,
    const float* __restrict__ Dp, float* __restrict__ y) {
  const int tid = threadIdx.x;
  const int s = tid & 15;
  const int cl = tid >> 4;
  const int blk = blockIdx.x;
  const int cg = blk & 63;
  const int chunk = (blk >> 6) & 15;
  const int b = blk >> 10;
  const int c = cg * 16 + cl;
  const float Acs = -__expf(A_log[c * DS + s]);
  const int t0 = chunk * CL;
  const float* dp = delta + ((size_t)b * L_SEQ + t0) * DI + c;
  const float* hp = h + ((size_t)b * L_SEQ + t0) * DI + c;
  const float* Bp = Bm + ((size_t)b * L_SEQ + t0) * DS + s;
  float* yp = y + ((size_t)b * L_SEQ + t0) * DI + c;
  const float* zp = xz + ((size_t)b * L_SEQ + t0) * (2 * DI) + DI + c;
  const float Dc = Dp[c];
  float state = sinit[(((size_t)b * NC + chunk) * DI + c) * DS + s];
  for (int t = 0; t < CL; ++t) {
    const float dt = dp[(size_t)t * DI];
    const float ht = hp[(size_t)t * DI];
    const float bt = Bp[(size_t)t * DS];
    state = __expf(dt * Acs) * state + dt * bt * ht;
    float yv = state * bt;
    yv += __shfl_xor(yv, 1);
    yv += __shfl_xor(yv, 2);
    yv += __shfl_xor(yv, 4);
    yv += __shfl_xor(yv, 8);
    if (s == 0) {
      const float z = zp[(size_t)t * (2 * DI)];
      yp[(size_t)t * DI] = (yv + Dc * ht) * silu_f(z);
    }
  }
}

extern "C" void kernel_launch(void* const* d_in, const int* in_sizes, int n_in,
                              void* d_out, int out_size, void* d_ws, size_t ws_size,
                              hipStream_t stream) {
  const float* x      = (const float*)d_in[0];
  const float* W_in   = (const float*)d_in[1];
  const float* conv_w = (const float*)d_in[2];
  const float* conv_b = (const float*)d_in[3];
  const float* W_x    = (const float*)d_in[4];
  const float* W_dt   = (const float*)d_in[5];
  const float* b_dt   = (const float*)d_in[6];
  const float* A_log  = (const float*)d_in[7];
  const float* D_par  = (const float*)d_in[8];
  const float* W_out  = (const float*)d_in[9];
  float* out = (float*)d_out;

  const int rows = NB * L_SEQ;  // 4096

  float* xz    = (float*)d_ws;                        // rows * 2048
  float* h     = xz + (size_t)rows * (2 * DI);        // rows * 1024
  float* delta = h + (size_t)rows * DI;               // rows * 1024 (aliased as y in phase3)
  float* Bm    = delta + (size_t)rows * DI;           // rows * 16
  float* aprod = Bm + (size_t)rows * DS;              // 2*16*1024*16 = 512K floats
  float* blocal= aprod + (size_t)NB * NC * DI * DS;
  float* sinit = blocal + (size_t)NB * NC * DI * DS;
  float* yb    = delta;  // y overwrites delta in phase3 (safe: same-wave read-before-write)

  // 1) xz = x @ W_in^T
  gemm_nt<0><<<dim3((2 * DI) / 64, rows / 64), 256, 0, stream>>>(
      x, DM, W_in, DM, nullptr, xz, 2 * DI, rows, 2 * DI, DM);
  // 2) depthwise conv + silu -> h
  conv_silu_kernel<<<(rows * DI) / 256, 256, 0, stream>>>(xz, conv_w, conv_b, h);
  // 3) delta = softplus(h @ W_dt^T + b_dt)
  gemm_nt<1><<<dim3(DI / 64, rows / 64), 256, 0, stream>>>(
      h, DI, W_dt, DI, b_dt, delta, DI, rows, DI, DI);
  // 3b) Bmat = h @ W_x[16:32]^T
  xproj_kernel<<<(rows * DS) / 256, 256, 0, stream>>>(h, W_x, Bm);
  // 4) chunked scan
  scan_phase1<<<NB * NC * (DI / 16), 256, 0, stream>>>(delta, h, Bm, A_log, aprod, blocal);
  scan_phase2<<<(NB * DI * DS) / 256, 256, 0, stream>>>(aprod, blocal, sinit);
  scan_phase3<<<NB * NC * (DI / 16), 256, 0, stream>>>(delta, h, Bm, A_log, sinit, xz, D_par, yb);
  // 5) out = yb @ W_out^T
  gemm_nt<0><<<dim3(DM / 64, rows / 64), 256, 0, stream>>>(
      yb, DI, W_out, DI, nullptr, out, DM, rows, DM, DI);
}

// Round 3
// 433.822 us; speedup vs baseline: 2.8489x; 1.2127x over previous
//
#include <hip/hip_runtime.h>
#include <cstddef>
#include <cstdint>

#define NB 2
#define L_SEQ 2048
#define DM 512
#define DS 16
#define DI 1024
#define NC 16
#define CL (L_SEQ/NC)

typedef __attribute__((ext_vector_type(4))) float f32x4;
typedef __attribute__((ext_vector_type(8))) short bf16x8;

__device__ __forceinline__ float softplus_f(float x) {
  return (x > 20.f) ? x : log1pf(expf(x));
}
__device__ __forceinline__ float silu_f(float x) {
  return x / (1.f + expf(-x));
}
__device__ __forceinline__ ushort f2bf(float f) {
  uint32_t u = __float_as_uint(f);
  return (ushort)((u + 0x7fffu + ((u >> 16) & 1u)) >> 16);
}
__device__ __forceinline__ float bf2f(ushort h) {
  return __uint_as_float(((uint32_t)h) << 16);
}

__device__ __forceinline__ void gload16(const void* g, ushort* lds_wave_base) {
  __builtin_amdgcn_global_load_lds(
      (const __attribute__((address_space(1))) void*)g,
      (__attribute__((address_space(3))) void*)lds_wave_base, 16, 0, 0);
}

// fp32 -> bf16 hi/lo split, vectorized by 4
__global__ __launch_bounds__(256) void split_bf16(
    const float* __restrict__ in, ushort* __restrict__ hi,
    ushort* __restrict__ lo, int n4) {
  int i = blockIdx.x * 256 + threadIdx.x;
  if (i >= n4) return;
  float4 v = ((const float4*)in)[i];
  ushort h0 = f2bf(v.x), h1 = f2bf(v.y), h2 = f2bf(v.z), h3 = f2bf(v.w);
  ((ushort4*)hi)[i] = make_ushort4(h0, h1, h2, h3);
  ((ushort4*)lo)[i] = make_ushort4(
      f2bf(v.x - bf2f(h0)), f2bf(v.y - bf2f(h1)),
      f2bf(v.z - bf2f(h2)), f2bf(v.w - bf2f(h3)));
}

// y stored strided in xz xi-cols (ld 2048) -> packed hi/lo
__global__ __launch_bounds__(256) void split_bf16_strided(
    const float* __restrict__ in, ushort* __restrict__ hi,
    ushort* __restrict__ lo) {
  int i = blockIdx.x * 256 + threadIdx.x;  // 1M float4 groups
  int r = i >> 8, cq = i & 255;
  float4 v = ((const float4*)(in + (size_t)r * 2048))[cq];
  ushort h0 = f2bf(v.x), h1 = f2bf(v.y), h2 = f2bf(v.z), h3 = f2bf(v.w);
  ((ushort4*)hi)[i] = make_ushort4(h0, h1, h2, h3);
  ((ushort4*)lo)[i] = make_ushort4(
      f2bf(v.x - bf2f(h0)), f2bf(v.y - bf2f(h1)),
      f2bf(v.z - bf2f(h2)), f2bf(v.w - bf2f(h3)));
}

// split-bf16 MFMA GEMM: C[M,N] = (Ahi+Alo)[M,K] @ (Bhi+Blo)[N,K]^T (drop lo*lo)
// 128x128 tile, 4 waves (2x2), 16x16x32 bf16 MFMA, BK=32.
// LDS staged via global_load_lds w=16, k-slot XOR swizzle (slot ^ (row>>1)&3).
template <int ACT>
__global__ __launch_bounds__(256) void gemm_mfma(
    const ushort* __restrict__ Ahi, const ushort* __restrict__ Alo, int lda,
    const ushort* __restrict__ Bhi, const ushort* __restrict__ Blo, int ldb,
    const float* __restrict__ bias, float* __restrict__ C, int ldc, int K) {
  __shared__ ushort As[4096];  // [128 rows][32 k] bf16, swizzled 16B slots
  __shared__ ushort Bs[4096];
  const int tid = threadIdx.x;
  const int lane = tid & 63;
  const int wave = tid >> 6;
  const int wr = wave >> 1, wc = wave & 1;
  const int m0 = blockIdx.y * 128, n0 = blockIdx.x * 128;

  // staging: issue0 rows 0..63 (e=tid), issue1 rows 64..127 (e=tid+256)
  const int r0 = tid >> 2;
  const int r1 = r0 + 64;
  const int kg = (tid & 3) ^ ((r0 >> 1) & 3);  // bits1-2 same for r0,r1
  const size_t aoff0 = (size_t)(m0 + r0) * lda + kg * 8;
  const size_t aoff1 = (size_t)(m0 + r1) * lda + kg * 8;
  const size_t boff0 = (size_t)(n0 + r0) * ldb + kg * 8;
  const size_t boff1 = (size_t)(n0 + r1) * ldb + kg * 8;
  ushort* lA0 = As + wave * 512;
  ushort* lA1 = As + 2048 + wave * 512;
  ushort* lB0 = Bs + wave * 512;
  ushort* lB1 = Bs + 2048 + wave * 512;

  // fragment reads: row = wr*64+m*16+fr, k-slot = fq ^ ((fr>>1)&3)
  const int fr = lane & 15, fq = lane >> 4;
  const int kswz = fq ^ ((fr >> 1) & 3);
  int aoffs[4], boffs[4];
#pragma unroll
  for (int m = 0; m < 4; m++) aoffs[m] = (wr * 64 + m * 16 + fr) * 32 + kswz * 8;
#pragma unroll
  for (int n = 0; n < 4; n++) boffs[n] = (wc * 64 + n * 16 + fr) * 32 + kswz * 8;

  f32x4 acc[4][4];
#pragma unroll
  for (int m = 0; m < 4; m++)
#pragma unroll
    for (int n = 0; n < 4; n++) acc[m][n] = (f32x4){0.f, 0.f, 0.f, 0.f};

  const int ksteps = K >> 5;
  const int nsteps = 3 * ksteps;
  for (int s = 0; s < nsteps; ++s) {
    const int phase = (s >= 2 * ksteps) ? 2 : ((s >= ksteps) ? 1 : 0);
    const int kk = (s - phase * ksteps) << 5;
    const ushort* Asrc = (phase == 1) ? Alo : Ahi;
    const ushort* Bsrc = (phase == 2) ? Blo : Bhi;
    __syncthreads();  // prev-iter LDS reads done
    gload16(Asrc + aoff0 + kk, lA0);
    gload16(Asrc + aoff1 + kk, lA1);
    gload16(Bsrc + boff0 + kk, lB0);
    gload16(Bsrc + boff1 + kk, lB1);
    __syncthreads();  // drains vmcnt -> LDS tile ready
    bf16x8 av[4], bv[4];
#pragma unroll
    for (int m = 0; m < 4; m++) av[m] = *(const bf16x8*)(As + aoffs[m]);
#pragma unroll
    for (int n = 0; n < 4; n++) bv[n] = *(const bf16x8*)(Bs + boffs[n]);
#pragma unroll
    for (int m = 0; m < 4; m++)
#pragma unroll
      for (int n = 0; n < 4; n++)
        acc[m][n] = __builtin_amdgcn_mfma_f32_16x16x32_bf16(av[m], bv[n], acc[m][n], 0, 0, 0);
  }

#pragma unroll
  for (int m = 0; m < 4; m++) {
    const int row = m0 + wr * 64 + m * 16 + fq * 4;
#pragma unroll
    for (int n = 0; n < 4; n++) {
      const int col = n0 + wc * 64 + n * 16 + fr;
      float bcol = (ACT == 1) ? bias[col] : 0.f;
#pragma unroll
      for (int j = 0; j < 4; j++) {
        float v = acc[m][n][j];
        if (ACT == 1) v = softplus_f(v + bcol);
        C[(size_t)(row + j) * ldc + col] = v;
      }
    }
  }
}

// depthwise causal conv (k=4) + SiLU; emits h fp32 and bf16 hi/lo split
__global__ __launch_bounds__(256) void conv_silu_kernel(
    const float* __restrict__ xz, const float* __restrict__ conv_w,
    const float* __restrict__ conv_b, float* __restrict__ h,
    ushort* __restrict__ h_hi, ushort* __restrict__ h_lo) {
  const int idx = blockIdx.x * 256 + threadIdx.x;
  const int c = idx & (DI - 1);
  const int r = idx >> 10;
  const int l = r & (L_SEQ - 1);
  const float w0 = conv_w[c * 4 + 0];
  const float w1 = conv_w[c * 4 + 1];
  const float w2 = conv_w[c * 4 + 2];
  const float w3 = conv_w[c * 4 + 3];
  const float* xp = xz + (size_t)r * (2 * DI) + c;
  float acc = conv_b[c];
  if (l >= 3) acc += xp[-3 * 2 * DI] * w0;
  if (l >= 2) acc += xp[-2 * 2 * DI] * w1;
  if (l >= 1) acc += xp[-1 * 2 * DI] * w2;
  acc += xp[0] * w3;
  const float hv = silu_f(acc);
  h[idx] = hv;
  const ushort hh = f2bf(hv);
  h_hi[idx] = hh;
  h_lo[idx] = f2bf(hv - bf2f(hh));
}

// Bmat[r][s] = dot(h[r][:], W_x[16+s][:])
__global__ __launch_bounds__(256) void xproj_kernel(
    const float* __restrict__ h, const float* __restrict__ W_x,
    float* __restrict__ Bm) {
  const int idx = blockIdx.x * 256 + threadIdx.x;
  const int s = idx & 15;
  const int r = idx >> 4;
  const float* hp = h + (size_t)r * DI;
  const float* wp = W_x + (size_t)(DS + s) * DI;
  float acc = 0.f;
  for (int k = 0; k < DI; k += 4) {
    float4 hv = *(const float4*)(hp + k);
    float4 wv = *(const float4*)(wp + k);
    acc += hv.x * wv.x + hv.y * wv.y + hv.z * wv.z + hv.w * wv.w;
  }
  Bm[idx] = acc;
}

// ---- chunked selective scan ----
__global__ __launch_bounds__(256) void scan_phase1(
    const float* __restrict__ delta, const float* __restrict__ h,
    const float* __restrict__ Bm, const float* __restrict__ A_log,
    float* __restrict__ aprod, float* __restrict__ blocal) {
  const int tid = threadIdx.x;
  const int s = tid & 15;
  const int cl = tid >> 4;
  const int blk = blockIdx.x;
  const int cg = blk & 63;
  const int chunk = (blk >> 6) & 15;
  const int b = blk >> 10;
  const int c = cg * 16 + cl;
  const float Acs = -__expf(A_log[c * DS + s]);
  const int t0 = chunk * CL;
  const float* dp = delta + ((size_t)b * L_SEQ + t0) * DI + c;
  const float* hp = h + ((size_t)b * L_SEQ + t0) * DI + c;
  const float* Bp = Bm + ((size_t)b * L_SEQ + t0) * DS + s;
  float state = 0.f, sdt = 0.f;
  for (int t = 0; t < CL; ++t) {
    const float dt = dp[(size_t)t * DI];
    const float ht = hp[(size_t)t * DI];
    const float bt = Bp[(size_t)t * DS];
    sdt += dt;
    state = __expf(dt * Acs) * state + dt * bt * ht;
  }
  const size_t o = (((size_t)b * NC + chunk) * DI + c) * DS + s;
  aprod[o] = __expf(Acs * sdt);
  blocal[o] = state;
}

__global__ __launch_bounds__(256) void scan_phase2(
    const float* __restrict__ aprod, const float* __restrict__ blocal,
    float* __restrict__ sinit) {
  const int idx = blockIdx.x * 256 + threadIdx.x;
  const int b = idx >> 14;
  const int cs = idx & 16383;
  float st = 0.f;
  for (int ch = 0; ch < NC; ++ch) {
    const size_t o = (size_t)(b * NC + ch) * (DI * DS) + cs;
    const float a = aprod[o];
    const float bl = blocal[o];
    sinit[o] = st;
    st = a * st + bl;
  }
}

// phase3: rerun chunk with init state; fused gate; y -> xz xi-cols (ld 2048)
__global__ __launch_bounds__(256) void scan_phase3(
    const float* __restrict__ delta, const float* __restrict__ h,
    const float* __restrict__ Bm, const float* __restrict__ A_log,
    const float* __restrict__ sinit, float* __restrict__ xz,
    const float* __restrict__ Dp) {
  const int tid = threadIdx.x;
  const int s = tid & 15;
  const int cl = tid >> 4;
  const int blk = blockIdx.x;
  const int cg = blk & 63;
  const int chunk = (blk >> 6) & 15;
  const int b = blk >> 10;
  const int c = cg * 16 + cl;
  const float Acs = -__expf(A_log[c * DS + s]);
  const int t0 = chunk * CL;
  const float* dp = delta + ((size_t)b * L_SEQ + t0) * DI + c;
  const float* hp = h + ((size_t)b * L_SEQ + t0) * DI + c;
  const float* Bp = Bm + ((size_t)b * L_SEQ + t0) * DS + s;
  float* yp = xz + ((size_t)b * L_SEQ + t0) * (2 * DI) + c;          // xi cols
  const float* zp = xz + ((size_t)b * L_SEQ + t0) * (2 * DI) + DI + c;  // z cols
  const float Dc = Dp[c];
  float state = sinit[(((size_t)b * NC + chunk) * DI + c) * DS + s];
  for (int t = 0; t < CL; ++t) {
    const float dt = dp[(size_t)t * DI];
    const float ht = hp[(size_t)t * DI];
    const float bt = Bp[(size_t)t * DS];
    state = __expf(dt * Acs) * state + dt * bt * ht;
    float yv = state * bt;
    yv += __shfl_xor(yv, 1);
    yv += __shfl_xor(yv, 2);
    yv += __shfl_xor(yv, 4);
    yv += __shfl_xor(yv, 8);
    if (s == 0) {
      const float z = zp[(size_t)t * (2 * DI)];
      yp[(size_t)t * (2 * DI)] = (yv + Dc * ht) * silu_f(z);
    }
  }
}

extern "C" void kernel_launch(void* const* d_in, const int* in_sizes, int n_in,
                              void* d_out, int out_size, void* d_ws, size_t ws_size,
                              hipStream_t stream) {
  const float* x      = (const float*)d_in[0];
  const float* W_in   = (const float*)d_in[1];
  const float* conv_w = (const float*)d_in[2];
  const float* conv_b = (const float*)d_in[3];
  const float* W_x    = (const float*)d_in[4];
  const float* W_dt   = (const float*)d_in[5];
  const float* b_dt   = (const float*)d_in[6];
  const float* A_log  = (const float*)d_in[7];
  const float* D_par  = (const float*)d_in[8];
  const float* W_out  = (const float*)d_in[9];
  float* out = (float*)d_out;

  const int rows = NB * L_SEQ;  // 4096

  // ws layout (floats)
  float* xz     = (float*)d_ws;                       // 8M
  float* h      = xz + (size_t)(8u << 20);            // 4M
  float* delta  = h + (size_t)(4u << 20);             // 4M (reused: y_hi/y_lo)
  float* Bm     = delta + (size_t)(4u << 20);         // 64K
  float* aprod  = Bm + (size_t)(64u << 10);           // 512K
  float* blocal = aprod + (size_t)(512u << 10);       // 512K
  float* sinit  = blocal + (size_t)(512u << 10);      // 512K
  float* wreg   = sinit + (size_t)(512u << 10);       // 1.5M floats
  ushort* Wdt_hi  = (ushort*)wreg;                    // 1M elems
  ushort* Wdt_lo  = Wdt_hi + (size_t)(1u << 20);
  ushort* Wout_hi = Wdt_lo + (size_t)(1u << 20);      // 512K elems
  ushort* Wout_lo = Wout_hi + (size_t)(512u << 10);
  float* xreg   = wreg + (size_t)((3u << 20) / 2);    // 4M floats region
  ushort* x_hi  = (ushort*)xreg;                      // 2M elems
  ushort* x_lo  = x_hi + (size_t)(2u << 20);
  ushort* Win_hi = x_lo + (size_t)(2u << 20);         // 1M elems
  ushort* Win_lo = Win_hi + (size_t)(1u << 20);
  ushort* h_hi  = (ushort*)xreg;                      // overlay (x dead after GEMM1)
  ushort* h_lo  = h_hi + (size_t)(4u << 20);
  ushort* y_hi  = (ushort*)delta;                     // overlay (delta dead after phase3)
  ushort* y_lo  = y_hi + (size_t)(4u << 20);

  // 0) weight/input bf16 hi-lo splits
  split_bf16<<<2048, 256, 0, stream>>>(x, x_hi, x_lo, rows * DM / 4);
  split_bf16<<<1024, 256, 0, stream>>>(W_in, Win_hi, Win_lo, 2 * DI * DM / 4);
  split_bf16<<<1024, 256, 0, stream>>>(W_dt, Wdt_hi, Wdt_lo, DI * DI / 4);
  split_bf16<<<512, 256, 0, stream>>>(W_out, Wout_hi, Wout_lo, DM * DI / 4);

  // 1) xz = x @ W_in^T   M=4096 N=2048 K=512
  gemm_mfma<0><<<dim3(16, 32), 256, 0, stream>>>(
      x_hi, x_lo, DM, Win_hi, Win_lo, DM, nullptr, xz, 2 * DI, DM);
  // 2) conv + silu -> h (+ hi/lo)
  conv_silu_kernel<<<(rows * DI) / 256, 256, 0, stream>>>(xz, conv_w, conv_b, h, h_hi, h_lo);
  // 3) delta = softplus(h @ W_dt^T + b_dt)   M=4096 N=1024 K=1024
  gemm_mfma<1><<<dim3(8, 32), 256, 0, stream>>>(
      h_hi, h_lo, DI, Wdt_hi, Wdt_lo, DI, b_dt, delta, DI, DI);
  // 3b) Bmat
  xproj_kernel<<<(rows * DS) / 256, 256, 0, stream>>>(h, W_x, Bm);
  // 4) chunked scan
  scan_phase1<<<NB * NC * (DI / 16), 256, 0, stream>>>(delta, h, Bm, A_log, aprod, blocal);
  scan_phase2<<<(NB * DI * DS) / 256, 256, 0, stream>>>(aprod, blocal, sinit);
  scan_phase3<<<NB * NC * (DI / 16), 256, 0, stream>>>(delta, h, Bm, A_log, sinit, xz, D_par);
  // 5) y split -> hi/lo (reads xz xi-cols strided)
  split_bf16_strided<<<4096, 256, 0, stream>>>(xz, y_hi, y_lo);
  // 6) out = y @ W_out^T   M=4096 N=512 K=1024
  gemm_mfma<0><<<dim3(4, 32), 256, 0, stream>>>(
      y_hi, y_lo, DI, Wout_hi, Wout_lo, DI, nullptr, out, DM, DI);
}

// Round 4
// 317.408 us; speedup vs baseline: 3.8938x; 1.3668x over previous
//
#include <hip/hip_runtime.h>
#include <cstddef>
#include <cstdint>

#define NB 2
#define L_SEQ 2048
#define DM 512
#define DS 16
#define DI 1024
#define NC 16
#define CL (L_SEQ/NC)

typedef __attribute__((ext_vector_type(4))) float f32x4;
typedef __attribute__((ext_vector_type(8))) short bf16x8;

__device__ __forceinline__ float softplus_f(float x) {
  return (x > 20.f) ? x : log1pf(expf(x));
}
__device__ __forceinline__ float silu_f(float x) {
  return x / (1.f + expf(-x));
}
__device__ __forceinline__ ushort f2bf(float f) {
  uint32_t u = __float_as_uint(f);
  return (ushort)((u + 0x7fffu + ((u >> 16) & 1u)) >> 16);
}
__device__ __forceinline__ float bf2f(ushort h) {
  return __uint_as_float(((uint32_t)h) << 16);
}

__device__ __forceinline__ void gload16(const void* g, ushort* lds_wave_base) {
  __builtin_amdgcn_global_load_lds(
      (const __attribute__((address_space(1))) void*)g,
      (__attribute__((address_space(3))) void*)lds_wave_base, 16, 0, 0);
}

// fp32 -> bf16 hi/lo split, vectorized by 4
__global__ __launch_bounds__(256) void split_bf16(
    const float* __restrict__ in, ushort* __restrict__ hi,
    ushort* __restrict__ lo, int n4) {
  int i = blockIdx.x * 256 + threadIdx.x;
  if (i >= n4) return;
  float4 v = ((const float4*)in)[i];
  ushort h0 = f2bf(v.x), h1 = f2bf(v.y), h2 = f2bf(v.z), h3 = f2bf(v.w);
  ((ushort4*)hi)[i] = make_ushort4(h0, h1, h2, h3);
  ((ushort4*)lo)[i] = make_ushort4(
      f2bf(v.x - bf2f(h0)), f2bf(v.y - bf2f(h1)),
      f2bf(v.z - bf2f(h2)), f2bf(v.w - bf2f(h3)));
}

// split-bf16 MFMA GEMM: C = (Ahi+Alo) @ (Bhi+Blo)^T, lo*lo dropped.
// BM=128 x BN tile, 4 waves (2x2), 16x16x32 bf16 MFMA, BK=32.
// Interleaved 3-pass: stage Ahi/Alo/Bhi/Blo per k-step, 3 MFMA batches.
// Double-buffered LDS, prefetch next step before compute (T3 2-phase).
template <int BN, int ACT>
__global__ __launch_bounds__(256, 2) void gemm_mfma(
    const ushort* __restrict__ Ahi, const ushort* __restrict__ Alo, int lda,
    const ushort* __restrict__ Bhi, const ushort* __restrict__ Blo, int ldb,
    const float* __restrict__ bias, float* __restrict__ C, int ldc, int K) {
  constexpr int BM = 128;
  constexpr int AT = BM * 32;           // ushorts per A tile (8KB)
  constexpr int BT = BN * 32;
  constexpr int BUF = 2 * AT + 2 * BT;  // one dbuf half
  constexpr int MR = 4, NR = BN / 32;   // per-wave frag counts (64 x BN/2)
  __shared__ __align__(16) ushort lds[2 * BUF];

  const int tid = threadIdx.x;
  const int lane = tid & 63;
  const int wave = tid >> 6;
  const int wr = wave >> 1, wc = wave & 1;

  // bijective XCD swizzle (all launches have nwg % 8 == 0)
  const int nx = gridDim.x;
  const int nwg = nx * gridDim.y;
  int bid = blockIdx.y * nx + blockIdx.x;
  bid = (bid & 7) * (nwg >> 3) + (bid >> 3);
  const int m0 = (bid / nx) * BM;
  const int n0 = (bid % nx) * BN;

  // staging: thread -> row tid>>2, k-slot (tid&3) pre-swizzled on global side
  const int r0 = tid >> 2;
  const int kg = (tid & 3) ^ ((r0 >> 1) & 3);
  const size_t aoff0 = (size_t)(m0 + r0) * lda + kg * 8;
  const size_t aoff1 = (size_t)(m0 + r0 + 64) * lda + kg * 8;
  const size_t boff0 = (size_t)(n0 + r0) * ldb + kg * 8;
  const size_t boff1 = (size_t)(n0 + r0 + 64) * ldb + kg * 8;  // BN==128 only

  // fragment reads: row = wr*64+m*16+fr, k-slot = fq ^ ((fr>>1)&3)
  const int fr = lane & 15, fq = lane >> 4;
  const int kswz = fq ^ ((fr >> 1) & 3);
  int aoffs[MR], boffs[NR];
#pragma unroll
  for (int m = 0; m < MR; m++) aoffs[m] = (wr * 64 + m * 16 + fr) * 32 + kswz * 8;
#pragma unroll
  for (int n = 0; n < NR; n++) boffs[n] = (wc * (BN / 2) + n * 16 + fr) * 32 + kswz * 8;

  f32x4 acc[MR][NR];
#pragma unroll
  for (int m = 0; m < MR; m++)
#pragma unroll
    for (int n = 0; n < NR; n++) acc[m][n] = (f32x4){0.f, 0.f, 0.f, 0.f};

  const int nsteps = K >> 5;

#define STAGE(bufi, kk)                                              \
  {                                                                  \
    ushort* base = lds + (bufi) * BUF;                               \
    gload16(Ahi + aoff0 + (kk), base + wave * 512);                  \
    gload16(Ahi + aoff1 + (kk), base + 2048 + wave * 512);           \
    gload16(Alo + aoff0 + (kk), base + AT + wave * 512);             \
    gload16(Alo + aoff1 + (kk), base + AT + 2048 + wave * 512);      \
    gload16(Bhi + boff0 + (kk), base + 2 * AT + wave * 512);         \
    gload16(Blo + boff0 + (kk), base + 2 * AT + BT + wave * 512);    \
    if (BN == 128) {                                                 \
      gload16(Bhi + boff1 + (kk), base + 2 * AT + 2048 + wave * 512);\
      gload16(Blo + boff1 + (kk), base + 2 * AT + BT + 2048 + wave * 512);\
    }                                                                \
  }

#define COMPUTE(bufi)                                                          \
  {                                                                            \
    const ushort* base = lds + (bufi) * BUF;                                   \
    bf16x8 ah[MR], al[MR], bh[NR], bl[NR];                                     \
    _Pragma("unroll")                                                          \
    for (int m = 0; m < MR; m++) ah[m] = *(const bf16x8*)(base + aoffs[m]);    \
    _Pragma("unroll")                                                          \
    for (int m = 0; m < MR; m++) al[m] = *(const bf16x8*)(base + AT + aoffs[m]);\
    _Pragma("unroll")                                                          \
    for (int n = 0; n < NR; n++) bh[n] = *(const bf16x8*)(base + 2 * AT + boffs[n]);\
    _Pragma("unroll")                                                          \
    for (int n = 0; n < NR; n++) bl[n] = *(const bf16x8*)(base + 2 * AT + BT + boffs[n]);\
    _Pragma("unroll")                                                          \
    for (int m = 0; m < MR; m++)                                               \
      _Pragma("unroll")                                                        \
      for (int n = 0; n < NR; n++)                                             \
        acc[m][n] = __builtin_amdgcn_mfma_f32_16x16x32_bf16(ah[m], bh[n], acc[m][n], 0, 0, 0);\
    _Pragma("unroll")                                                          \
    for (int m = 0; m < MR; m++)                                               \
      _Pragma("unroll")                                                        \
      for (int n = 0; n < NR; n++)                                             \
        acc[m][n] = __builtin_amdgcn_mfma_f32_16x16x32_bf16(al[m], bh[n], acc[m][n], 0, 0, 0);\
    _Pragma("unroll")                                                          \
    for (int m = 0; m < MR; m++)                                               \
      _Pragma("unroll")                                                        \
      for (int n = 0; n < NR; n++)                                             \
        acc[m][n] = __builtin_amdgcn_mfma_f32_16x16x32_bf16(ah[m], bl[n], acc[m][n], 0, 0, 0);\
  }

  STAGE(0, 0);
  __syncthreads();  // drains vmcnt(0): buf0 ready
  for (int t = 0; t < nsteps - 1; ++t) {
    STAGE((t + 1) & 1, (t + 1) << 5);  // prefetch next (stays in flight)
    COMPUTE(t & 1);
    __syncthreads();  // drains vmcnt: next buf ready; cur buf reads done
  }
  COMPUTE((nsteps - 1) & 1);
#undef STAGE
#undef COMPUTE

#pragma unroll
  for (int m = 0; m < MR; m++) {
    const int row = m0 + wr * 64 + m * 16 + fq * 4;
#pragma unroll
    for (int n = 0; n < NR; n++) {
      const int col = n0 + wc * (BN / 2) + n * 16 + fr;
      float bcol = (ACT == 1) ? bias[col] : 0.f;
#pragma unroll
      for (int j = 0; j < 4; j++) {
        float v = acc[m][n][j];
        if (ACT == 1) v = softplus_f(v + bcol);
        C[(size_t)(row + j) * ldc + col] = v;
      }
    }
  }
}

// depthwise causal conv (k=4) + SiLU; emits h fp32 and bf16 hi/lo split
__global__ __launch_bounds__(256) void conv_silu_kernel(
    const float* __restrict__ xz, const float* __restrict__ conv_w,
    const float* __restrict__ conv_b, float* __restrict__ h,
    ushort* __restrict__ h_hi, ushort* __restrict__ h_lo) {
  const int idx = blockIdx.x * 256 + threadIdx.x;
  const int c = idx & (DI - 1);
  const int r = idx >> 10;
  const int l = r & (L_SEQ - 1);
  const float w0 = conv_w[c * 4 + 0];
  const float w1 = conv_w[c * 4 + 1];
  const float w2 = conv_w[c * 4 + 2];
  const float w3 = conv_w[c * 4 + 3];
  const float* xp = xz + (size_t)r * (2 * DI) + c;
  float acc = conv_b[c];
  if (l >= 3) acc += xp[-3 * 2 * DI] * w0;
  if (l >= 2) acc += xp[-2 * 2 * DI] * w1;
  if (l >= 1) acc += xp[-1 * 2 * DI] * w2;
  acc += xp[0] * w3;
  const float hv = silu_f(acc);
  h[idx] = hv;
  const ushort hh = f2bf(hv);
  h_hi[idx] = hh;
  h_lo[idx] = f2bf(hv - bf2f(hh));
}

// Bmat[r][s] = dot(h[r][:], W_x[16+s][:])
__global__ __launch_bounds__(256) void xproj_kernel(
    const float* __restrict__ h, const float* __restrict__ W_x,
    float* __restrict__ Bm) {
  const int idx = blockIdx.x * 256 + threadIdx.x;
  const int s = idx & 15;
  const int r = idx >> 4;
  const float* hp = h + (size_t)r * DI;
  const float* wp = W_x + (size_t)(DS + s) * DI;
  float acc = 0.f;
  for (int k = 0; k < DI; k += 4) {
    float4 hv = *(const float4*)(hp + k);
    float4 wv = *(const float4*)(wp + k);
    acc += hv.x * wv.x + hv.y * wv.y + hv.z * wv.z + hv.w * wv.w;
  }
  Bm[idx] = acc;
}

// ---- chunked selective scan ----
__global__ __launch_bounds__(256) void scan_phase1(
    const float* __restrict__ delta, const float* __restrict__ h,
    const float* __restrict__ Bm, const float* __restrict__ A_log,
    float* __restrict__ aprod, float* __restrict__ blocal) {
  const int tid = threadIdx.x;
  const int s = tid & 15;
  const int cl = tid >> 4;
  const int blk = blockIdx.x;
  const int cg = blk & 63;
  const int chunk = (blk >> 6) & 15;
  const int b = blk >> 10;
  const int c = cg * 16 + cl;
  const float Acs = -__expf(A_log[c * DS + s]);
  const int t0 = chunk * CL;
  const float* dp = delta + ((size_t)b * L_SEQ + t0) * DI + c;
  const float* hp = h + ((size_t)b * L_SEQ + t0) * DI + c;
  const float* Bp = Bm + ((size_t)b * L_SEQ + t0) * DS + s;
  float state = 0.f, sdt = 0.f;
  for (int t = 0; t < CL; ++t) {
    const float dt = dp[(size_t)t * DI];
    const float ht = hp[(size_t)t * DI];
    const float bt = Bp[(size_t)t * DS];
    sdt += dt;
    state = __expf(dt * Acs) * state + dt * bt * ht;
  }
  const size_t o = (((size_t)b * NC + chunk) * DI + c) * DS + s;
  aprod[o] = __expf(Acs * sdt);
  blocal[o] = state;
}

__global__ __launch_bounds__(256) void scan_phase2(
    const float* __restrict__ aprod, const float* __restrict__ blocal,
    float* __restrict__ sinit) {
  const int idx = blockIdx.x * 256 + threadIdx.x;
  const int b = idx >> 14;
  const int cs = idx & 16383;
  float st = 0.f;
  for (int ch = 0; ch < NC; ++ch) {
    const size_t o = (size_t)(b * NC + ch) * (DI * DS) + cs;
    const float a = aprod[o];
    const float bl = blocal[o];
    sinit[o] = st;
    st = a * st + bl;
  }
}

// phase3: rerun chunk with init state; fused gate; fused bf16 hi/lo split of y.
// y_hi/y_lo written into the dead xi-columns of xz: row r's 4KB xi region holds
// [1024 ushort hi][1024 ushort lo]; z-columns (float offset 1024) untouched.
__global__ __launch_bounds__(256) void scan_phase3(
    const float* __restrict__ delta, const float* __restrict__ h,
    const float* __restrict__ Bm, const float* __restrict__ A_log,
    const float* __restrict__ sinit, float* __restrict__ xz,
    const float* __restrict__ Dp) {
  const int tid = threadIdx.x;
  const int s = tid & 15;
  const int cl = tid >> 4;
  const int blk = blockIdx.x;
  const int cg = blk & 63;
  const int chunk = (blk >> 6) & 15;
  const int b = blk >> 10;
  const int c = cg * 16 + cl;
  const float Acs = -__expf(A_log[c * DS + s]);
  const int t0 = chunk * CL;
  const size_t row0 = (size_t)b * L_SEQ + t0;
  const float* dp = delta + row0 * DI + c;
  const float* hp = h + row0 * DI + c;
  const float* Bp = Bm + row0 * DS + s;
  const float* zp = xz + row0 * (2 * DI) + DI + c;
  ushort* yh = (ushort*)(xz + row0 * (2 * DI)) + c;         // row stride 4096 ushorts
  ushort* yl = yh + 1024;
  const float Dc = Dp[c];
  float state = sinit[((row0 / L_SEQ * NC + chunk) * DI + c) * DS + s];
  state = sinit[(((size_t)b * NC + chunk) * DI + c) * DS + s];
  for (int t = 0; t < CL; ++t) {
    const float dt = dp[(size_t)t * DI];
    const float ht = hp[(size_t)t * DI];
    const float bt = Bp[(size_t)t * DS];
    state = __expf(dt * Acs) * state + dt * bt * ht;
    float yv = state * bt;
    yv += __shfl_xor(yv, 1);
    yv += __shfl_xor(yv, 2);
    yv += __shfl_xor(yv, 4);
    yv += __shfl_xor(yv, 8);
    if (s == 0) {
      const float z = zp[(size_t)t * (2 * DI)];
      const float g = (yv + Dc * ht) * silu_f(z);
      const ushort gh = f2bf(g);
      yh[(size_t)t * 4096] = gh;
      yl[(size_t)t * 4096] = f2bf(g - bf2f(gh));
    }
  }
}

extern "C" void kernel_launch(void* const* d_in, const int* in_sizes, int n_in,
                              void* d_out, int out_size, void* d_ws, size_t ws_size,
                              hipStream_t stream) {
  const float* x      = (const float*)d_in[0];
  const float* W_in   = (const float*)d_in[1];
  const float* conv_w = (const float*)d_in[2];
  const float* conv_b = (const float*)d_in[3];
  const float* W_x    = (const float*)d_in[4];
  const float* W_dt   = (const float*)d_in[5];
  const float* b_dt   = (const float*)d_in[6];
  const float* A_log  = (const float*)d_in[7];
  const float* D_par  = (const float*)d_in[8];
  const float* W_out  = (const float*)d_in[9];
  float* out = (float*)d_out;

  const int rows = NB * L_SEQ;  // 4096

  // ws layout (floats) — identical footprint to round 3 (~92 MB)
  float* xz     = (float*)d_ws;                       // 8M floats
  float* h      = xz + (size_t)(8u << 20);            // 4M
  float* delta  = h + (size_t)(4u << 20);             // 4M
  float* Bm     = delta + (size_t)(4u << 20);         // 64K
  float* aprod  = Bm + (size_t)(64u << 10);           // 512K
  float* blocal = aprod + (size_t)(512u << 10);       // 512K
  float* sinit  = blocal + (size_t)(512u << 10);      // 512K
  float* wreg   = sinit + (size_t)(512u << 10);       // 1.5M floats
  ushort* Wdt_hi  = (ushort*)wreg;
  ushort* Wdt_lo  = Wdt_hi + (size_t)(1u << 20);
  ushort* Wout_hi = Wdt_lo + (size_t)(1u << 20);
  ushort* Wout_lo = Wout_hi + (size_t)(512u << 10);
  float* xreg   = wreg + (size_t)((3u << 20) / 2);    // 4M floats region
  ushort* x_hi  = (ushort*)xreg;
  ushort* x_lo  = x_hi + (size_t)(2u << 20);
  ushort* Win_hi = x_lo + (size_t)(2u << 20);
  ushort* Win_lo = Win_hi + (size_t)(1u << 20);
  ushort* h_hi  = (ushort*)xreg;                      // overlay (x/W_in dead after GEMM1)
  ushort* h_lo  = h_hi + (size_t)(4u << 20);
  ushort* y_hi  = (ushort*)xz;                        // xi-cols overlay, lda 4096
  ushort* y_lo  = y_hi + 1024;

  // 0) bf16 hi/lo splits
  split_bf16<<<2048, 256, 0, stream>>>(x, x_hi, x_lo, rows * DM / 4);
  split_bf16<<<1024, 256, 0, stream>>>(W_in, Win_hi, Win_lo, 2 * DI * DM / 4);
  split_bf16<<<1024, 256, 0, stream>>>(W_dt, Wdt_hi, Wdt_lo, DI * DI / 4);
  split_bf16<<<512, 256, 0, stream>>>(W_out, Wout_hi, Wout_lo, DM * DI / 4);

  // 1) xz = x @ W_in^T   M=4096 N=2048 K=512
  gemm_mfma<128, 0><<<dim3(16, 32), 256, 0, stream>>>(
      x_hi, x_lo, DM, Win_hi, Win_lo, DM, nullptr, xz, 2 * DI, DM);
  // 2) conv + silu -> h (+ hi/lo)
  conv_silu_kernel<<<(rows * DI) / 256, 256, 0, stream>>>(xz, conv_w, conv_b, h, h_hi, h_lo);
  // 3) delta = softplus(h @ W_dt^T + b_dt)   M=4096 N=1024 K=1024
  gemm_mfma<64, 1><<<dim3(16, 32), 256, 0, stream>>>(
      h_hi, h_lo, DI, Wdt_hi, Wdt_lo, DI, b_dt, delta, DI, DI);
  // 3b) Bmat
  xproj_kernel<<<(rows * DS) / 256, 256, 0, stream>>>(h, W_x, Bm);
  // 4) chunked scan (phase3 fuses gate + y bf16 split into xz xi-cols)
  scan_phase1<<<NB * NC * (DI / 16), 256, 0, stream>>>(delta, h, Bm, A_log, aprod, blocal);
  scan_phase2<<<(NB * DI * DS) / 256, 256, 0, stream>>>(aprod, blocal, sinit);
  scan_phase3<<<NB * NC * (DI / 16), 256, 0, stream>>>(delta, h, Bm, A_log, sinit, xz, D_par);
  // 5) out = y @ W_out^T   M=4096 N=512 K=1024   (A = y_hi/y_lo in xz, lda=4096)
  gemm_mfma<64, 0><<<dim3(8, 32), 256, 0, stream>>>(
      y_hi, y_lo, 4096, Wout_hi, Wout_lo, DI, nullptr, out, DM, DI);
}

// Round 5
// 231.725 us; speedup vs baseline: 5.3336x; 1.3698x over previous
//
#include <hip/hip_runtime.h>
#include <cstddef>
#include <cstdint>

#define NB 2
#define L_SEQ 2048
#define DM 512
#define DS 16
#define DI 1024
#define NC 64
#define CL (L_SEQ/NC)   // 32

typedef __attribute__((ext_vector_type(4))) float f32x4;
typedef __attribute__((ext_vector_type(8))) short bf16x8;

__device__ __forceinline__ float softplus_f(float x) {
  return (x > 20.f) ? x : log1pf(expf(x));
}
__device__ __forceinline__ float silu_f(float x) {
  return x / (1.f + expf(-x));
}
__device__ __forceinline__ ushort f2bf(float f) {
  uint32_t u = __float_as_uint(f);
  return (ushort)((u + 0x7fffu + ((u >> 16) & 1u)) >> 16);
}
__device__ __forceinline__ float bf2f(ushort h) {
  return __uint_as_float(((uint32_t)h) << 16);
}

__device__ __forceinline__ void gload16(const void* g, ushort* lds_wave_base) {
  __builtin_amdgcn_global_load_lds(
      (const __attribute__((address_space(1))) void*)g,
      (__attribute__((address_space(3))) void*)lds_wave_base, 16, 0, 0);
}

// fp32 -> bf16 hi/lo split, vectorized by 4
__global__ __launch_bounds__(256) void split_bf16(
    const float* __restrict__ in, ushort* __restrict__ hi,
    ushort* __restrict__ lo, int n4) {
  int i = blockIdx.x * 256 + threadIdx.x;
  if (i >= n4) return;
  float4 v = ((const float4*)in)[i];
  ushort h0 = f2bf(v.x), h1 = f2bf(v.y), h2 = f2bf(v.z), h3 = f2bf(v.w);
  ((ushort4*)hi)[i] = make_ushort4(h0, h1, h2, h3);
  ((ushort4*)lo)[i] = make_ushort4(
      f2bf(v.x - bf2f(h0)), f2bf(v.y - bf2f(h1)),
      f2bf(v.z - bf2f(h2)), f2bf(v.w - bf2f(h3)));
}

// split-bf16 MFMA GEMM: C = (Ahi+Alo) @ (Bhi+Blo)^T, lo*lo dropped.
// BM=128 x BN tile, 4 waves (2x2), 16x16x32 bf16 MFMA, BK=32.
// Double-buffered LDS, prefetch next step before compute (T3 2-phase).
template <int BN, int ACT>
__global__ __launch_bounds__(256, 2) void gemm_mfma(
    const ushort* __restrict__ Ahi, const ushort* __restrict__ Alo, int lda,
    const ushort* __restrict__ Bhi, const ushort* __restrict__ Blo, int ldb,
    const float* __restrict__ bias, float* __restrict__ C, int ldc, int K) {
  constexpr int BM = 128;
  constexpr int AT = BM * 32;           // ushorts per A tile (8KB)
  constexpr int BT = BN * 32;
  constexpr int BUF = 2 * AT + 2 * BT;  // one dbuf half
  constexpr int MR = 4, NR = BN / 32;   // per-wave frag counts (64 x BN/2)
  __shared__ __align__(16) ushort lds[2 * BUF];

  const int tid = threadIdx.x;
  const int lane = tid & 63;
  const int wave = tid >> 6;
  const int wr = wave >> 1, wc = wave & 1;

  // bijective XCD swizzle (all launches have nwg % 8 == 0)
  const int nx = gridDim.x;
  const int nwg = nx * gridDim.y;
  int bid = blockIdx.y * nx + blockIdx.x;
  bid = (bid & 7) * (nwg >> 3) + (bid >> 3);
  const int m0 = (bid / nx) * BM;
  const int n0 = (bid % nx) * BN;

  // staging: thread -> row tid>>2, k-slot (tid&3) pre-swizzled on global side
  const int r0 = tid >> 2;
  const int kg = (tid & 3) ^ ((r0 >> 1) & 3);
  const size_t aoff0 = (size_t)(m0 + r0) * lda + kg * 8;
  const size_t aoff1 = (size_t)(m0 + r0 + 64) * lda + kg * 8;
  const size_t boff0 = (size_t)(n0 + r0) * ldb + kg * 8;
  const size_t boff1 = (size_t)(n0 + r0 + 64) * ldb + kg * 8;  // BN==128 only

  // fragment reads: row = wr*64+m*16+fr, k-slot = fq ^ ((fr>>1)&3)
  const int fr = lane & 15, fq = lane >> 4;
  const int kswz = fq ^ ((fr >> 1) & 3);
  int aoffs[MR], boffs[NR];
#pragma unroll
  for (int m = 0; m < MR; m++) aoffs[m] = (wr * 64 + m * 16 + fr) * 32 + kswz * 8;
#pragma unroll
  for (int n = 0; n < NR; n++) boffs[n] = (wc * (BN / 2) + n * 16 + fr) * 32 + kswz * 8;

  f32x4 acc[MR][NR];
#pragma unroll
  for (int m = 0; m < MR; m++)
#pragma unroll
    for (int n = 0; n < NR; n++) acc[m][n] = (f32x4){0.f, 0.f, 0.f, 0.f};

  const int nsteps = K >> 5;

#define STAGE(bufi, kk)                                              \
  {                                                                  \
    ushort* base = lds + (bufi) * BUF;                               \
    gload16(Ahi + aoff0 + (kk), base + wave * 512);                  \
    gload16(Ahi + aoff1 + (kk), base + 2048 + wave * 512);           \
    gload16(Alo + aoff0 + (kk), base + AT + wave * 512);             \
    gload16(Alo + aoff1 + (kk), base + AT + 2048 + wave * 512);      \
    gload16(Bhi + boff0 + (kk), base + 2 * AT + wave * 512);         \
    gload16(Blo + boff0 + (kk), base + 2 * AT + BT + wave * 512);    \
    if (BN == 128) {                                                 \
      gload16(Bhi + boff1 + (kk), base + 2 * AT + 2048 + wave * 512);\
      gload16(Blo + boff1 + (kk), base + 2 * AT + BT + 2048 + wave * 512);\
    }                                                                \
  }

#define COMPUTE(bufi)                                                          \
  {                                                                            \
    const ushort* base = lds + (bufi) * BUF;                                   \
    bf16x8 ah[MR], al[MR], bh[NR], bl[NR];                                     \
    _Pragma("unroll")                                                          \
    for (int m = 0; m < MR; m++) ah[m] = *(const bf16x8*)(base + aoffs[m]);    \
    _Pragma("unroll")                                                          \
    for (int m = 0; m < MR; m++) al[m] = *(const bf16x8*)(base + AT + aoffs[m]);\
    _Pragma("unroll")                                                          \
    for (int n = 0; n < NR; n++) bh[n] = *(const bf16x8*)(base + 2 * AT + boffs[n]);\
    _Pragma("unroll")                                                          \
    for (int n = 0; n < NR; n++) bl[n] = *(const bf16x8*)(base + 2 * AT + BT + boffs[n]);\
    _Pragma("unroll")                                                          \
    for (int m = 0; m < MR; m++)                                               \
      _Pragma("unroll")                                                        \
      for (int n = 0; n < NR; n++)                                             \
        acc[m][n] = __builtin_amdgcn_mfma_f32_16x16x32_bf16(ah[m], bh[n], acc[m][n], 0, 0, 0);\
    _Pragma("unroll")                                                          \
    for (int m = 0; m < MR; m++)                                               \
      _Pragma("unroll")                                                        \
      for (int n = 0; n < NR; n++)                                             \
        acc[m][n] = __builtin_amdgcn_mfma_f32_16x16x32_bf16(al[m], bh[n], acc[m][n], 0, 0, 0);\
    _Pragma("unroll")                                                          \
    for (int m = 0; m < MR; m++)                                               \
      _Pragma("unroll")                                                        \
      for (int n = 0; n < NR; n++)                                             \
        acc[m][n] = __builtin_amdgcn_mfma_f32_16x16x32_bf16(ah[m], bl[n], acc[m][n], 0, 0, 0);\
  }

  STAGE(0, 0);
  __syncthreads();  // drains vmcnt(0): buf0 ready
  for (int t = 0; t < nsteps - 1; ++t) {
    STAGE((t + 1) & 1, (t + 1) << 5);  // prefetch next (stays in flight)
    COMPUTE(t & 1);
    __syncthreads();  // drains vmcnt: next buf ready; cur buf reads done
  }
  COMPUTE((nsteps - 1) & 1);
#undef STAGE
#undef COMPUTE

#pragma unroll
  for (int m = 0; m < MR; m++) {
    const int row = m0 + wr * 64 + m * 16 + fq * 4;
#pragma unroll
    for (int n = 0; n < NR; n++) {
      const int col = n0 + wc * (BN / 2) + n * 16 + fr;
      float bcol = (ACT == 1) ? bias[col] : 0.f;
#pragma unroll
      for (int j = 0; j < 4; j++) {
        float v = acc[m][n][j];
        if (ACT == 1) v = softplus_f(v + bcol);
        C[(size_t)(row + j) * ldc + col] = v;
      }
    }
  }
}

// depthwise causal conv (k=4) + SiLU; emits h fp32 and bf16 hi/lo split
__global__ __launch_bounds__(256) void conv_silu_kernel(
    const float* __restrict__ xz, const float* __restrict__ conv_w,
    const float* __restrict__ conv_b, float* __restrict__ h,
    ushort* __restrict__ h_hi, ushort* __restrict__ h_lo) {
  const int idx = blockIdx.x * 256 + threadIdx.x;
  const int c = idx & (DI - 1);
  const int r = idx >> 10;
  const int l = r & (L_SEQ - 1);
  const float w0 = conv_w[c * 4 + 0];
  const float w1 = conv_w[c * 4 + 1];
  const float w2 = conv_w[c * 4 + 2];
  const float w3 = conv_w[c * 4 + 3];
  const float* xp = xz + (size_t)r * (2 * DI) + c;
  float acc = conv_b[c];
  if (l >= 3) acc += xp[-3 * 2 * DI] * w0;
  if (l >= 2) acc += xp[-2 * 2 * DI] * w1;
  if (l >= 1) acc += xp[-1 * 2 * DI] * w2;
  acc += xp[0] * w3;
  const float hv = silu_f(acc);
  h[idx] = hv;
  const ushort hh = f2bf(hv);
  h_hi[idx] = hh;
  h_lo[idx] = f2bf(hv - bf2f(hh));
}

// Bmat[r][s] = dot(h[r][:], W_x[16+s][:])
__global__ __launch_bounds__(256) void xproj_kernel(
    const float* __restrict__ h, const float* __restrict__ W_x,
    float* __restrict__ Bm) {
  const int idx = blockIdx.x * 256 + threadIdx.x;
  const int s = idx & 15;
  const int r = idx >> 4;
  const float* hp = h + (size_t)r * DI;
  const float* wp = W_x + (size_t)(DS + s) * DI;
  float acc = 0.f;
  for (int k = 0; k < DI; k += 4) {
    float4 hv = *(const float4*)(hp + k);
    float4 wv = *(const float4*)(wp + k);
    acc += hv.x * wv.x + hv.y * wv.y + hv.z * wv.z + hv.w * wv.w;
  }
  Bm[idx] = acc;
}

// ---- chunked selective scan, channel-per-thread ----
// grid: [b(2)][chunk(64)][cblk(4)] = 512 blocks x 256 thr; thread owns channel c,
// 16 states in registers (s-loops fully unrolled -> static reg indexing).
__global__ __launch_bounds__(256) void scan_phase1(
    const float* __restrict__ delta, const float* __restrict__ h,
    const float* __restrict__ Bm, const float* __restrict__ A_log,
    float* __restrict__ aprod, float* __restrict__ blocal) {
  __shared__ float sB[CL * DS];  // 2KB
  const int tid = threadIdx.x;
  const int bid = blockIdx.x;
  const int cblk = bid & 3;
  const int chunk = (bid >> 2) & (NC - 1);
  const int b = bid >> 8;
  const int c = cblk * 256 + tid;
  const size_t row0 = (size_t)b * L_SEQ + chunk * CL;
  ((float2*)sB)[tid] = ((const float2*)(Bm + row0 * DS))[tid];
  __syncthreads();

  float Acs[DS], state[DS];
#pragma unroll
  for (int s = 0; s < DS; s += 4) {
    float4 al = *(const float4*)(A_log + (size_t)c * DS + s);
    Acs[s + 0] = -__expf(al.x);
    Acs[s + 1] = -__expf(al.y);
    Acs[s + 2] = -__expf(al.z);
    Acs[s + 3] = -__expf(al.w);
    state[s + 0] = 0.f; state[s + 1] = 0.f; state[s + 2] = 0.f; state[s + 3] = 0.f;
  }
  const float* dp = delta + row0 * DI + c;
  const float* hp = h + row0 * DI + c;
  float sdt = 0.f;
  for (int t = 0; t < CL; ++t) {
    const float dt = dp[(size_t)t * DI];
    const float ht = hp[(size_t)t * DI];
    const float dth = dt * ht;
    sdt += dt;
#pragma unroll
    for (int s = 0; s < DS; ++s)
      state[s] = __expf(dt * Acs[s]) * state[s] + dth * sB[t * DS + s];
  }
  const size_t o = (((size_t)b * NC + chunk) * DI + c) * DS;
#pragma unroll
  for (int s = 0; s < DS; s += 4) {
    *(float4*)(aprod + o + s) = make_float4(
        __expf(Acs[s] * sdt), __expf(Acs[s + 1] * sdt),
        __expf(Acs[s + 2] * sdt), __expf(Acs[s + 3] * sdt));
    *(float4*)(blocal + o + s) = make_float4(state[s], state[s + 1], state[s + 2], state[s + 3]);
  }
}

// serial scan over chunk summaries; writes sinit IN PLACE over aprod
__global__ __launch_bounds__(256) void scan_phase2(
    float* __restrict__ aprod, const float* __restrict__ blocal) {
  const int idx = blockIdx.x * 256 + threadIdx.x;  // NB*DI*DS = 32768
  const int b = idx >> 14;
  const int cs = idx & 16383;
  float st = 0.f;
  for (int ch = 0; ch < NC; ++ch) {
    const size_t o = (size_t)(b * NC + ch) * (DI * DS) + cs;
    const float a = aprod[o];
    const float bl = blocal[o];
    aprod[o] = st;   // sinit for this chunk
    st = a * st + bl;
  }
}

// phase3: rerun chunk with init state; fused gate + bf16 hi/lo split of y.
// y_hi/y_lo written into the dead xi-columns of xz (row = 4096 ushorts:
// [1024 hi][1024 lo]); z float columns at +1024 untouched.
__global__ __launch_bounds__(256) void scan_phase3(
    const float* __restrict__ delta, const float* __restrict__ h,
    const float* __restrict__ Bm, const float* __restrict__ A_log,
    const float* __restrict__ sinit, float* __restrict__ xz,
    const float* __restrict__ Dp) {
  __shared__ float sB[CL * DS];
  const int tid = threadIdx.x;
  const int bid = blockIdx.x;
  const int cblk = bid & 3;
  const int chunk = (bid >> 2) & (NC - 1);
  const int b = bid >> 8;
  const int c = cblk * 256 + tid;
  const size_t row0 = (size_t)b * L_SEQ + chunk * CL;
  ((float2*)sB)[tid] = ((const float2*)(Bm + row0 * DS))[tid];
  __syncthreads();

  float Acs[DS], state[DS];
  const size_t o = (((size_t)b * NC + chunk) * DI + c) * DS;
#pragma unroll
  for (int s = 0; s < DS; s += 4) {
    float4 al = *(const float4*)(A_log + (size_t)c * DS + s);
    Acs[s + 0] = -__expf(al.x);
    Acs[s + 1] = -__expf(al.y);
    Acs[s + 2] = -__expf(al.z);
    Acs[s + 3] = -__expf(al.w);
    float4 sv = *(const float4*)(sinit + o + s);
    state[s + 0] = sv.x; state[s + 1] = sv.y; state[s + 2] = sv.z; state[s + 3] = sv.w;
  }
  const float* dp = delta + row0 * DI + c;
  const float* hp = h + row0 * DI + c;
  const float* zp = xz + row0 * (2 * DI) + DI + c;
  ushort* yrow = (ushort*)(xz + row0 * (2 * DI)) + c;  // row stride 4096 ushorts
  const float Dc = Dp[c];
  for (int t = 0; t < CL; ++t) {
    const float dt = dp[(size_t)t * DI];
    const float ht = hp[(size_t)t * DI];
    const float z = zp[(size_t)t * (2 * DI)];
    const float dth = dt * ht;
    float yv = 0.f;
#pragma unroll
    for (int s = 0; s < DS; ++s) {
      const float bt = sB[t * DS + s];
      state[s] = __expf(dt * Acs[s]) * state[s] + dth * bt;
      yv += state[s] * bt;
    }
    const float g = (yv + Dc * ht) * silu_f(z);
    const ushort gh = f2bf(g);
    yrow[(size_t)t * 4096] = gh;
    yrow[(size_t)t * 4096 + 1024] = f2bf(g - bf2f(gh));
  }
}

extern "C" void kernel_launch(void* const* d_in, const int* in_sizes, int n_in,
                              void* d_out, int out_size, void* d_ws, size_t ws_size,
                              hipStream_t stream) {
  const float* x      = (const float*)d_in[0];
  const float* W_in   = (const float*)d_in[1];
  const float* conv_w = (const float*)d_in[2];
  const float* conv_b = (const float*)d_in[3];
  const float* W_x    = (const float*)d_in[4];
  const float* W_dt   = (const float*)d_in[5];
  const float* b_dt   = (const float*)d_in[6];
  const float* A_log  = (const float*)d_in[7];
  const float* D_par  = (const float*)d_in[8];
  const float* W_out  = (const float*)d_in[9];
  float* out = (float*)d_out;

  const int rows = NB * L_SEQ;  // 4096

  // ws layout (floats) — ~92 MB total, unchanged
  float* xz     = (float*)d_ws;                       // 8M floats
  float* h      = xz + (size_t)(8u << 20);            // 4M
  float* delta  = h + (size_t)(4u << 20);             // 4M
  float* Bm     = delta + (size_t)(4u << 20);         // 64K
  float* spare  = Bm + (size_t)(64u << 10);           // 1.5M (old scan bufs, unused)
  float* wreg   = spare + (size_t)((3u << 20) / 2);   // 1.5M floats
  ushort* Wdt_hi  = (ushort*)wreg;
  ushort* Wdt_lo  = Wdt_hi + (size_t)(1u << 20);
  ushort* Wout_hi = Wdt_lo + (size_t)(1u << 20);
  ushort* Wout_lo = Wout_hi + (size_t)(512u << 10);
  float* xreg   = wreg + (size_t)((3u << 20) / 2);    // 4M floats region
  ushort* x_hi  = (ushort*)xreg;
  ushort* x_lo  = x_hi + (size_t)(2u << 20);
  ushort* Win_hi = x_lo + (size_t)(2u << 20);
  ushort* Win_lo = Win_hi + (size_t)(1u << 20);
  ushort* h_hi  = (ushort*)xreg;                      // overlay (x/W_in dead after GEMM1)
  ushort* h_lo  = h_hi + (size_t)(4u << 20);
  float* aprod  = xreg;                               // overlay (h_hi/h_lo dead after GEMM2)
  float* blocal = aprod + (size_t)(2u << 20);         // NB*NC*DI*DS = 2M floats each
  ushort* y_hi  = (ushort*)xz;                        // xi-cols overlay, lda 4096
  ushort* y_lo  = y_hi + 1024;

  // 0) bf16 hi/lo splits
  split_bf16<<<2048, 256, 0, stream>>>(x, x_hi, x_lo, rows * DM / 4);
  split_bf16<<<1024, 256, 0, stream>>>(W_in, Win_hi, Win_lo, 2 * DI * DM / 4);
  split_bf16<<<1024, 256, 0, stream>>>(W_dt, Wdt_hi, Wdt_lo, DI * DI / 4);
  split_bf16<<<512, 256, 0, stream>>>(W_out, Wout_hi, Wout_lo, DM * DI / 4);

  // 1) xz = x @ W_in^T   M=4096 N=2048 K=512
  gemm_mfma<128, 0><<<dim3(16, 32), 256, 0, stream>>>(
      x_hi, x_lo, DM, Win_hi, Win_lo, DM, nullptr, xz, 2 * DI, DM);
  // 2) conv + silu -> h (+ hi/lo)
  conv_silu_kernel<<<(rows * DI) / 256, 256, 0, stream>>>(xz, conv_w, conv_b, h, h_hi, h_lo);
  // 3) delta = softplus(h @ W_dt^T + b_dt)   M=4096 N=1024 K=1024
  gemm_mfma<64, 1><<<dim3(16, 32), 256, 0, stream>>>(
      h_hi, h_lo, DI, Wdt_hi, Wdt_lo, DI, b_dt, delta, DI, DI);
  // 3b) Bmat
  xproj_kernel<<<(rows * DS) / 256, 256, 0, stream>>>(h, W_x, Bm);
  // 4) chunked scan (channel-per-thread; phase2 writes sinit in place over aprod)
  scan_phase1<<<NB * NC * (DI / 256), 256, 0, stream>>>(delta, h, Bm, A_log, aprod, blocal);
  scan_phase2<<<(NB * DI * DS) / 256, 256, 0, stream>>>(aprod, blocal);
  scan_phase3<<<NB * NC * (DI / 256), 256, 0, stream>>>(delta, h, Bm, A_log, aprod, xz, D_par);
  // 5) out = y @ W_out^T   M=4096 N=512 K=1024   (A = y_hi/y_lo in xz, lda=4096)
  gemm_mfma<64, 0><<<dim3(8, 32), 256, 0, stream>>>(
      y_hi, y_lo, 4096, Wout_hi, Wout_lo, DI, nullptr, out, DM, DI);
}

// Round 6
// 230.609 us; speedup vs baseline: 5.3594x; 1.0048x over previous
//
#include <hip/hip_runtime.h>
#include <cstddef>
#include <cstdint>

#define NB 2
#define L_SEQ 2048
#define DM 512
#define DS 16
#define DI 1024
#define NC 64
#define CL (L_SEQ/NC)   // 32

typedef __attribute__((ext_vector_type(4))) float f32x4;
typedef __attribute__((ext_vector_type(8))) short bf16x8;

__device__ __forceinline__ float softplus_f(float x) {
  return (x > 20.f) ? x : log1pf(expf(x));
}
__device__ __forceinline__ float silu_f(float x) {
  return x / (1.f + expf(-x));
}
__device__ __forceinline__ ushort f2bf(float f) {
  uint32_t u = __float_as_uint(f);
  return (ushort)((u + 0x7fffu + ((u >> 16) & 1u)) >> 16);
}
__device__ __forceinline__ float bf2f(ushort h) {
  return __uint_as_float(((uint32_t)h) << 16);
}

__device__ __forceinline__ void gload16(const void* g, ushort* lds_wave_base) {
  __builtin_amdgcn_global_load_lds(
      (const __attribute__((address_space(1))) void*)g,
      (__attribute__((address_space(3))) void*)lds_wave_base, 16, 0, 0);
}

template <int N>
__device__ __forceinline__ void wait_vm() {
  if constexpr (N == 0)      asm volatile("s_waitcnt vmcnt(0)" ::: "memory");
  else if constexpr (N == 4) asm volatile("s_waitcnt vmcnt(4)" ::: "memory");
  else if constexpr (N == 6) asm volatile("s_waitcnt vmcnt(6)" ::: "memory");
  else if constexpr (N == 8) asm volatile("s_waitcnt vmcnt(8)" ::: "memory");
}

// fp32 -> bf16 hi/lo split, vectorized by 4
__global__ __launch_bounds__(256) void split_bf16(
    const float* __restrict__ in, ushort* __restrict__ hi,
    ushort* __restrict__ lo, int n4) {
  int i = blockIdx.x * 256 + threadIdx.x;
  if (i >= n4) return;
  float4 v = ((const float4*)in)[i];
  ushort h0 = f2bf(v.x), h1 = f2bf(v.y), h2 = f2bf(v.z), h3 = f2bf(v.w);
  ((ushort4*)hi)[i] = make_ushort4(h0, h1, h2, h3);
  ((ushort4*)lo)[i] = make_ushort4(
      f2bf(v.x - bf2f(h0)), f2bf(v.y - bf2f(h1)),
      f2bf(v.z - bf2f(h2)), f2bf(v.w - bf2f(h3)));
}

// split-bf16 MFMA GEMM: C = (Ahi+Alo) @ (Bhi+Blo)^T, lo*lo dropped.
// BM x BN tile, 4 waves (2x2), 16x16x32 bf16 MFMA, BK=32.
// 3-buffer LDS, 2-deep prefetch, ONE raw s_barrier per K-step,
// counted s_waitcnt vmcnt(LPS) -- prefetch loads stay in flight (T3+T4).
template <int BM, int BN, int ACT>
__global__ __launch_bounds__(256) void gemm_mfma(
    const ushort* __restrict__ Ahi, const ushort* __restrict__ Alo, int lda,
    const ushort* __restrict__ Bhi, const ushort* __restrict__ Blo, int ldb,
    const float* __restrict__ bias, float* __restrict__ C, int ldc, int K) {
  constexpr int AT = BM * 32;           // ushorts per A tile
  constexpr int BT = BN * 32;
  constexpr int BUF = 2 * AT + 2 * BT;  // one buffer (hi+lo, A+B)
  constexpr int MR = BM / 32, NR = BN / 32;
  constexpr int LPS = (BM / 64) * 2 + (BN / 64) * 2;  // gloads per stage per thread
  __shared__ __align__(16) ushort lds[3 * BUF];

  const int tid = threadIdx.x;
  const int lane = tid & 63;
  const int wave = tid >> 6;
  const int wr = wave >> 1, wc = wave & 1;

  // bijective XCD swizzle (all launches have nwg % 8 == 0)
  const int nx = gridDim.x;
  const int nwg = nx * gridDim.y;
  int bid = blockIdx.y * nx + blockIdx.x;
  bid = (bid & 7) * (nwg >> 3) + (bid >> 3);
  const int m0 = (bid / nx) * BM;
  const int n0 = (bid % nx) * BN;

  // staging: thread -> row tid>>2, k-slot (tid&3) pre-swizzled on global side
  const int r0 = tid >> 2;
  const int kg = (tid & 3) ^ ((r0 >> 1) & 3);
  const size_t aoff0 = (size_t)(m0 + r0) * lda + kg * 8;
  const size_t aoff1 = (size_t)(m0 + r0 + 64) * lda + kg * 8;  // BM==128 only
  const size_t boff0 = (size_t)(n0 + r0) * ldb + kg * 8;

  // fragment reads: row_in_tile bits1-2 = fr bits1-2 -> kswz matches store swizzle
  const int fr = lane & 15, fq = lane >> 4;
  const int kswz = fq ^ ((fr >> 1) & 3);
  int aoffs[MR], boffs[NR];
#pragma unroll
  for (int m = 0; m < MR; m++) aoffs[m] = (wr * (BM / 2) + m * 16 + fr) * 32 + kswz * 8;
#pragma unroll
  for (int n = 0; n < NR; n++) boffs[n] = (wc * (BN / 2) + n * 16 + fr) * 32 + kswz * 8;

  f32x4 acc[MR][NR];
#pragma unroll
  for (int m = 0; m < MR; m++)
#pragma unroll
    for (int n = 0; n < NR; n++) acc[m][n] = (f32x4){0.f, 0.f, 0.f, 0.f};

  const int nsteps = K >> 5;

#define STAGE(base, kk)                                                     \
  {                                                                         \
    ushort* bp = (base);                                                    \
    gload16(Ahi + aoff0 + (kk), bp + wave * 512);                           \
    if constexpr (BM == 128) gload16(Ahi + aoff1 + (kk), bp + 2048 + wave * 512); \
    gload16(Alo + aoff0 + (kk), bp + AT + wave * 512);                      \
    if constexpr (BM == 128) gload16(Alo + aoff1 + (kk), bp + AT + 2048 + wave * 512); \
    gload16(Bhi + boff0 + (kk), bp + 2 * AT + wave * 512);                  \
    gload16(Blo + boff0 + (kk), bp + 2 * AT + BT + wave * 512);             \
  }

#define COMPUTE(base)                                                          \
  {                                                                            \
    const ushort* cp = (base);                                                 \
    bf16x8 ah[MR], al[MR], bh[NR], bl[NR];                                     \
    _Pragma("unroll")                                                          \
    for (int m = 0; m < MR; m++) ah[m] = *(const bf16x8*)(cp + aoffs[m]);      \
    _Pragma("unroll")                                                          \
    for (int m = 0; m < MR; m++) al[m] = *(const bf16x8*)(cp + AT + aoffs[m]); \
    _Pragma("unroll")                                                          \
    for (int n = 0; n < NR; n++) bh[n] = *(const bf16x8*)(cp + 2 * AT + boffs[n]); \
    _Pragma("unroll")                                                          \
    for (int n = 0; n < NR; n++) bl[n] = *(const bf16x8*)(cp + 2 * AT + BT + boffs[n]); \
    _Pragma("unroll")                                                          \
    for (int m = 0; m < MR; m++)                                               \
      _Pragma("unroll")                                                        \
      for (int n = 0; n < NR; n++)                                             \
        acc[m][n] = __builtin_amdgcn_mfma_f32_16x16x32_bf16(ah[m], bh[n], acc[m][n], 0, 0, 0); \
    _Pragma("unroll")                                                          \
    for (int m = 0; m < MR; m++)                                               \
      _Pragma("unroll")                                                        \
      for (int n = 0; n < NR; n++)                                             \
        acc[m][n] = __builtin_amdgcn_mfma_f32_16x16x32_bf16(al[m], bh[n], acc[m][n], 0, 0, 0); \
    _Pragma("unroll")                                                          \
    for (int m = 0; m < MR; m++)                                               \
      _Pragma("unroll")                                                        \
      for (int n = 0; n < NR; n++)                                             \
        acc[m][n] = __builtin_amdgcn_mfma_f32_16x16x32_bf16(ah[m], bl[n], acc[m][n], 0, 0, 0); \
  }

  // prologue: fill bufs 0,1
  STAGE(lds, 0);
  STAGE(lds + BUF, 32);
  int ocur = 0, onext = BUF, ofar = 2 * BUF;
  for (int t = 0; t < nsteps; ++t) {
    if (t == nsteps - 1) wait_vm<0>(); else wait_vm<LPS>();
    __builtin_amdgcn_s_barrier();       // all waves: buf[t] staged, buf[t-1] reads done
    if (t + 2 < nsteps) STAGE(lds + ofar, (t + 2) << 5);  // in flight across barriers
    COMPUTE(lds + ocur);
    int tmp = ocur; ocur = onext; onext = ofar; ofar = tmp;
  }
#undef STAGE
#undef COMPUTE

#pragma unroll
  for (int m = 0; m < MR; m++) {
    const int row = m0 + wr * (BM / 2) + m * 16 + fq * 4;
#pragma unroll
    for (int n = 0; n < NR; n++) {
      const int col = n0 + wc * (BN / 2) + n * 16 + fr;
      float bcol = (ACT == 1) ? bias[col] : 0.f;
#pragma unroll
      for (int j = 0; j < 4; j++) {
        float v = acc[m][n][j];
        if (ACT == 1) v = softplus_f(v + bcol);
        C[(size_t)(row + j) * ldc + col] = v;
      }
    }
  }
}

// depthwise causal conv (k=4) + SiLU; emits h fp32 and bf16 hi/lo split
__global__ __launch_bounds__(256) void conv_silu_kernel(
    const float* __restrict__ xz, const float* __restrict__ conv_w,
    const float* __restrict__ conv_b, float* __restrict__ h,
    ushort* __restrict__ h_hi, ushort* __restrict__ h_lo) {
  const int idx = blockIdx.x * 256 + threadIdx.x;
  const int c = idx & (DI - 1);
  const int r = idx >> 10;
  const int l = r & (L_SEQ - 1);
  const float w0 = conv_w[c * 4 + 0];
  const float w1 = conv_w[c * 4 + 1];
  const float w2 = conv_w[c * 4 + 2];
  const float w3 = conv_w[c * 4 + 3];
  const float* xp = xz + (size_t)r * (2 * DI) + c;
  float acc = conv_b[c];
  if (l >= 3) acc += xp[-3 * 2 * DI] * w0;
  if (l >= 2) acc += xp[-2 * 2 * DI] * w1;
  if (l >= 1) acc += xp[-1 * 2 * DI] * w2;
  acc += xp[0] * w3;
  const float hv = silu_f(acc);
  h[idx] = hv;
  const ushort hh = f2bf(hv);
  h_hi[idx] = hh;
  h_lo[idx] = f2bf(hv - bf2f(hh));
}

// Bmat[r][s] = dot(h[r][:], W_x[16+s][:])
__global__ __launch_bounds__(256) void xproj_kernel(
    const float* __restrict__ h, const float* __restrict__ W_x,
    float* __restrict__ Bm) {
  const int idx = blockIdx.x * 256 + threadIdx.x;
  const int s = idx & 15;
  const int r = idx >> 4;
  const float* hp = h + (size_t)r * DI;
  const float* wp = W_x + (size_t)(DS + s) * DI;
  float acc = 0.f;
  for (int k = 0; k < DI; k += 4) {
    float4 hv = *(const float4*)(hp + k);
    float4 wv = *(const float4*)(wp + k);
    acc += hv.x * wv.x + hv.y * wv.y + hv.z * wv.z + hv.w * wv.w;
  }
  Bm[idx] = acc;
}

// ---- chunked selective scan, channel-per-thread ----
__global__ __launch_bounds__(256) void scan_phase1(
    const float* __restrict__ delta, const float* __restrict__ h,
    const float* __restrict__ Bm, const float* __restrict__ A_log,
    float* __restrict__ aprod, float* __restrict__ blocal) {
  __shared__ float sB[CL * DS];  // 2KB
  const int tid = threadIdx.x;
  const int bid = blockIdx.x;
  const int cblk = bid & 3;
  const int chunk = (bid >> 2) & (NC - 1);
  const int b = bid >> 8;
  const int c = cblk * 256 + tid;
  const size_t row0 = (size_t)b * L_SEQ + chunk * CL;
  ((float2*)sB)[tid] = ((const float2*)(Bm + row0 * DS))[tid];
  __syncthreads();

  float Acs[DS], state[DS];
#pragma unroll
  for (int s = 0; s < DS; s += 4) {
    float4 al = *(const float4*)(A_log + (size_t)c * DS + s);
    Acs[s + 0] = -__expf(al.x);
    Acs[s + 1] = -__expf(al.y);
    Acs[s + 2] = -__expf(al.z);
    Acs[s + 3] = -__expf(al.w);
    state[s + 0] = 0.f; state[s + 1] = 0.f; state[s + 2] = 0.f; state[s + 3] = 0.f;
  }
  const float* dp = delta + row0 * DI + c;
  const float* hp = h + row0 * DI + c;
  float sdt = 0.f;
  for (int t = 0; t < CL; ++t) {
    const float dt = dp[(size_t)t * DI];
    const float ht = hp[(size_t)t * DI];
    const float dth = dt * ht;
    sdt += dt;
#pragma unroll
    for (int s = 0; s < DS; ++s)
      state[s] = __expf(dt * Acs[s]) * state[s] + dth * sB[t * DS + s];
  }
  const size_t o = (((size_t)b * NC + chunk) * DI + c) * DS;
#pragma unroll
  for (int s = 0; s < DS; s += 4) {
    *(float4*)(aprod + o + s) = make_float4(
        __expf(Acs[s] * sdt), __expf(Acs[s + 1] * sdt),
        __expf(Acs[s + 2] * sdt), __expf(Acs[s + 3] * sdt));
    *(float4*)(blocal + o + s) = make_float4(state[s], state[s + 1], state[s + 2], state[s + 3]);
  }
}

// serial scan over chunk summaries; writes sinit IN PLACE over aprod
__global__ __launch_bounds__(256) void scan_phase2(
    float* __restrict__ aprod, const float* __restrict__ blocal) {
  const int idx = blockIdx.x * 256 + threadIdx.x;  // NB*DI*DS = 32768
  const int b = idx >> 14;
  const int cs = idx & 16383;
  float st = 0.f;
  for (int ch = 0; ch < NC; ++ch) {
    const size_t o = (size_t)(b * NC + ch) * (DI * DS) + cs;
    const float a = aprod[o];
    const float bl = blocal[o];
    aprod[o] = st;   // sinit for this chunk
    st = a * st + bl;
  }
}

// phase3: rerun chunk with init state; fused gate + bf16 hi/lo split of y.
// y_hi/y_lo written into the dead xi-columns of xz (row = 4096 ushorts:
// [1024 hi][1024 lo]); z float columns at +1024 untouched.
__global__ __launch_bounds__(256) void scan_phase3(
    const float* __restrict__ delta, const float* __restrict__ h,
    const float* __restrict__ Bm, const float* __restrict__ A_log,
    const float* __restrict__ sinit, float* __restrict__ xz,
    const float* __restrict__ Dp) {
  __shared__ float sB[CL * DS];
  const int tid = threadIdx.x;
  const int bid = blockIdx.x;
  const int cblk = bid & 3;
  const int chunk = (bid >> 2) & (NC - 1);
  const int b = bid >> 8;
  const int c = cblk * 256 + tid;
  const size_t row0 = (size_t)b * L_SEQ + chunk * CL;
  ((float2*)sB)[tid] = ((const float2*)(Bm + row0 * DS))[tid];
  __syncthreads();

  float Acs[DS], state[DS];
  const size_t o = (((size_t)b * NC + chunk) * DI + c) * DS;
#pragma unroll
  for (int s = 0; s < DS; s += 4) {
    float4 al = *(const float4*)(A_log + (size_t)c * DS + s);
    Acs[s + 0] = -__expf(al.x);
    Acs[s + 1] = -__expf(al.y);
    Acs[s + 2] = -__expf(al.z);
    Acs[s + 3] = -__expf(al.w);
    float4 sv = *(const float4*)(sinit + o + s);
    state[s + 0] = sv.x; state[s + 1] = sv.y; state[s + 2] = sv.z; state[s + 3] = sv.w;
  }
  const float* dp = delta + row0 * DI + c;
  const float* hp = h + row0 * DI + c;
  const float* zp = xz + row0 * (2 * DI) + DI + c;
  ushort* yrow = (ushort*)(xz + row0 * (2 * DI)) + c;  // row stride 4096 ushorts
  const float Dc = Dp[c];
  for (int t = 0; t < CL; ++t) {
    const float dt = dp[(size_t)t * DI];
    const float ht = hp[(size_t)t * DI];
    const float z = zp[(size_t)t * (2 * DI)];
    const float dth = dt * ht;
    float yv = 0.f;
#pragma unroll
    for (int s = 0; s < DS; ++s) {
      const float bt = sB[t * DS + s];
      state[s] = __expf(dt * Acs[s]) * state[s] + dth * bt;
      yv += state[s] * bt;
    }
    const float g = (yv + Dc * ht) * silu_f(z);
    const ushort gh = f2bf(g);
    yrow[(size_t)t * 4096] = gh;
    yrow[(size_t)t * 4096 + 1024] = f2bf(g - bf2f(gh));
  }
}

extern "C" void kernel_launch(void* const* d_in, const int* in_sizes, int n_in,
                              void* d_out, int out_size, void* d_ws, size_t ws_size,
                              hipStream_t stream) {
  const float* x      = (const float*)d_in[0];
  const float* W_in   = (const float*)d_in[1];
  const float* conv_w = (const float*)d_in[2];
  const float* conv_b = (const float*)d_in[3];
  const float* W_x    = (const float*)d_in[4];
  const float* W_dt   = (const float*)d_in[5];
  const float* b_dt   = (const float*)d_in[6];
  const float* A_log  = (const float*)d_in[7];
  const float* D_par  = (const float*)d_in[8];
  const float* W_out  = (const float*)d_in[9];
  float* out = (float*)d_out;

  const int rows = NB * L_SEQ;  // 4096

  // ws layout (floats) — ~92 MB total
  float* xz     = (float*)d_ws;                       // 8M floats
  float* h      = xz + (size_t)(8u << 20);            // 4M
  float* delta  = h + (size_t)(4u << 20);             // 4M
  float* Bm     = delta + (size_t)(4u << 20);         // 64K
  float* spare  = Bm + (size_t)(64u << 10);           // 1.5M
  float* wreg   = spare + (size_t)((3u << 20) / 2);   // 1.5M floats
  ushort* Wdt_hi  = (ushort*)wreg;
  ushort* Wdt_lo  = Wdt_hi + (size_t)(1u << 20);
  ushort* Wout_hi = Wdt_lo + (size_t)(1u << 20);
  ushort* Wout_lo = Wout_hi + (size_t)(512u << 10);
  float* xreg   = wreg + (size_t)((3u << 20) / 2);    // 4M floats region
  ushort* x_hi  = (ushort*)xreg;
  ushort* x_lo  = x_hi + (size_t)(2u << 20);
  ushort* Win_hi = x_lo + (size_t)(2u << 20);
  ushort* Win_lo = Win_hi + (size_t)(1u << 20);
  ushort* h_hi  = (ushort*)xreg;                      // overlay (x/W_in dead after GEMM1)
  ushort* h_lo  = h_hi + (size_t)(4u << 20);
  float* aprod  = xreg;                               // overlay (h_hi/h_lo dead after GEMM2)
  float* blocal = aprod + (size_t)(2u << 20);         // NB*NC*DI*DS = 2M floats each
  ushort* y_hi  = (ushort*)xz;                        // xi-cols overlay, lda 4096
  ushort* y_lo  = y_hi + 1024;

  // 0) bf16 hi/lo splits
  split_bf16<<<2048, 256, 0, stream>>>(x, x_hi, x_lo, rows * DM / 4);
  split_bf16<<<1024, 256, 0, stream>>>(W_in, Win_hi, Win_lo, 2 * DI * DM / 4);
  split_bf16<<<1024, 256, 0, stream>>>(W_dt, Wdt_hi, Wdt_lo, DI * DI / 4);
  split_bf16<<<512, 256, 0, stream>>>(W_out, Wout_hi, Wout_lo, DM * DI / 4);

  // 1) xz = x @ W_in^T   M=4096 N=2048 K=512
  gemm_mfma<128, 64, 0><<<dim3(32, 32), 256, 0, stream>>>(
      x_hi, x_lo, DM, Win_hi, Win_lo, DM, nullptr, xz, 2 * DI, DM);
  // 2) conv + silu -> h (+ hi/lo)
  conv_silu_kernel<<<(rows * DI) / 256, 256, 0, stream>>>(xz, conv_w, conv_b, h, h_hi, h_lo);
  // 3) delta = softplus(h @ W_dt^T + b_dt)   M=4096 N=1024 K=1024
  gemm_mfma<128, 64, 1><<<dim3(16, 32), 256, 0, stream>>>(
      h_hi, h_lo, DI, Wdt_hi, Wdt_lo, DI, b_dt, delta, DI, DI);
  // 3b) Bmat
  xproj_kernel<<<(rows * DS) / 256, 256, 0, stream>>>(h, W_x, Bm);
  // 4) chunked scan
  scan_phase1<<<NB * NC * (DI / 256), 256, 0, stream>>>(delta, h, Bm, A_log, aprod, blocal);
  scan_phase2<<<(NB * DI * DS) / 256, 256, 0, stream>>>(aprod, blocal);
  scan_phase3<<<NB * NC * (DI / 256), 256, 0, stream>>>(delta, h, Bm, A_log, aprod, xz, D_par);
  // 5) out = y @ W_out^T   M=4096 N=512 K=1024   (A = y_hi/y_lo in xz, lda=4096)
  gemm_mfma<64, 64, 0><<<dim3(8, 64), 256, 0, stream>>>(
      y_hi, y_lo, 4096, Wout_hi, Wout_lo, DI, nullptr, out, DM, DI);
}

// Round 7
// 228.280 us; speedup vs baseline: 5.4141x; 1.0102x over previous
//
#include <hip/hip_runtime.h>
#include <cstddef>
#include <cstdint>

#define NB 2
#define L_SEQ 2048
#define DM 512
#define DS 16
#define DI 1024
#define NC 64
#define CL (L_SEQ/NC)   // 32

typedef __attribute__((ext_vector_type(4))) float f32x4;
typedef __attribute__((ext_vector_type(8))) short bf16x8;

__device__ __forceinline__ float softplus_f(float x) {
  return (x > 20.f) ? x : log1pf(expf(x));
}
__device__ __forceinline__ float silu_f(float x) {
  return x / (1.f + expf(-x));
}
__device__ __forceinline__ ushort f2bf(float f) {
  uint32_t u = __float_as_uint(f);
  return (ushort)((u + 0x7fffu + ((u >> 16) & 1u)) >> 16);
}
__device__ __forceinline__ float bf2f(ushort h) {
  return __uint_as_float(((uint32_t)h) << 16);
}

__device__ __forceinline__ void gload16(const void* g, ushort* lds_wave_base) {
  __builtin_amdgcn_global_load_lds(
      (const __attribute__((address_space(1))) void*)g,
      (__attribute__((address_space(3))) void*)lds_wave_base, 16, 0, 0);
}

template <int N>
__device__ __forceinline__ void wait_vm() {
  if constexpr (N == 0)      asm volatile("s_waitcnt vmcnt(0)" ::: "memory");
  else if constexpr (N == 3) asm volatile("s_waitcnt vmcnt(3)" ::: "memory");
  else if constexpr (N == 4) asm volatile("s_waitcnt vmcnt(4)" ::: "memory");
  else if constexpr (N == 6) asm volatile("s_waitcnt vmcnt(6)" ::: "memory");
}

// fp32 -> bf16 hi/lo split, vectorized by 4
__global__ __launch_bounds__(256) void split_bf16(
    const float* __restrict__ in, ushort* __restrict__ hi,
    ushort* __restrict__ lo, int n4) {
  int i = blockIdx.x * 256 + threadIdx.x;
  if (i >= n4) return;
  float4 v = ((const float4*)in)[i];
  ushort h0 = f2bf(v.x), h1 = f2bf(v.y), h2 = f2bf(v.z), h3 = f2bf(v.w);
  ((ushort4*)hi)[i] = make_ushort4(h0, h1, h2, h3);
  ((ushort4*)lo)[i] = make_ushort4(
      f2bf(v.x - bf2f(h0)), f2bf(v.y - bf2f(h1)),
      f2bf(v.z - bf2f(h2)), f2bf(v.w - bf2f(h3)));
}

// ---- 8-wave split-bf16 MFMA GEMM (BM=128, BN=64, 512 thr, 2x4 wave grid) ----
// 3-buffer LDS, 2-deep prefetch, one s_barrier + counted vmcnt(3) per K-step.
// Each thread stages exactly 3 gloads: Ahi, Alo, one of Bhi/Blo (by wave).
template <int ACT>
__global__ __launch_bounds__(512, 4) void gemm_mfma8(
    const ushort* __restrict__ Ahi, const ushort* __restrict__ Alo, int lda,
    const ushort* __restrict__ Bhi, const ushort* __restrict__ Blo, int ldb,
    const float* __restrict__ bias, float* __restrict__ C, int ldc, int K) {
  constexpr int BM = 128, BN = 64;
  constexpr int AT = BM * 32;           // 4096 ushorts (8KB)
  constexpr int BT = BN * 32;           // 2048 ushorts (4KB)
  constexpr int BUF = 2 * AT + 2 * BT;  // 12288 ushorts (24KB)
  constexpr int MR = 2, NR = 2;         // per-wave 32x32 output
  __shared__ __align__(16) ushort lds[3 * BUF];  // 72KB

  const int tid = threadIdx.x;
  const int lane = tid & 63;
  const int wave = tid >> 6;            // 0..7
  const int wr = wave >> 1;             // 0..3
  const int wc = wave & 1;              // 0..1

  // bijective XCD swizzle (all launches have nwg % 8 == 0)
  const int nx = gridDim.x;
  const int nwg = nx * gridDim.y;
  int bid = blockIdx.y * nx + blockIdx.x;
  bid = (bid & 7) * (nwg >> 3) + (bid >> 3);
  const int m0 = (bid / nx) * BM;
  const int n0 = (bid % nx) * BN;

  // A staging: thread -> row tid>>2 (0..127), k-slot (tid&3) pre-swizzled
  const int ra = tid >> 2;
  const int kga = (tid & 3) ^ ((ra >> 1) & 3);
  const size_t aoff = (size_t)(m0 + ra) * lda + kga * 8;
  // B staging: tq = tid&255 -> row tq>>2 (0..63); waves 0-3 stage Bhi, 4-7 Blo
  const int tq = tid & 255;
  const int rb = tq >> 2;
  const int kgb = (tq & 3) ^ ((rb >> 1) & 3);
  const size_t boff = (size_t)(n0 + rb) * ldb + kgb * 8;
  const ushort* Bsel = (wave < 4) ? Bhi : Blo;
  const int blds = 2 * AT + ((wave < 4) ? wave * 512 : BT + (wave - 4) * 512);

  // fragment reads: row = wr*32 + m*16 + fr; k-slot = fq ^ ((fr>>1)&3)
  const int fr = lane & 15, fq = lane >> 4;
  const int kswz = fq ^ ((fr >> 1) & 3);
  int aoffs[MR], boffs[NR];
#pragma unroll
  for (int m = 0; m < MR; m++) aoffs[m] = (wr * 32 + m * 16 + fr) * 32 + kswz * 8;
#pragma unroll
  for (int n = 0; n < NR; n++) boffs[n] = (wc * 32 + n * 16 + fr) * 32 + kswz * 8;

  f32x4 acc[MR][NR];
#pragma unroll
  for (int m = 0; m < MR; m++)
#pragma unroll
    for (int n = 0; n < NR; n++) acc[m][n] = (f32x4){0.f, 0.f, 0.f, 0.f};

  const int nsteps = K >> 5;

#define STAGE(base, kk)                                     \
  {                                                         \
    ushort* bp = (base);                                    \
    gload16(Ahi + aoff + (kk), bp + wave * 512);            \
    gload16(Alo + aoff + (kk), bp + AT + wave * 512);       \
    gload16(Bsel + boff + (kk), bp + blds);                 \
  }

#define COMPUTE(base)                                                          \
  {                                                                            \
    const ushort* cp = (base);                                                 \
    bf16x8 ah[MR], al[MR], bh[NR], bl[NR];                                     \
    _Pragma("unroll")                                                          \
    for (int m = 0; m < MR; m++) ah[m] = *(const bf16x8*)(cp + aoffs[m]);      \
    _Pragma("unroll")                                                          \
    for (int m = 0; m < MR; m++) al[m] = *(const bf16x8*)(cp + AT + aoffs[m]); \
    _Pragma("unroll")                                                          \
    for (int n = 0; n < NR; n++) bh[n] = *(const bf16x8*)(cp + 2 * AT + boffs[n]); \
    _Pragma("unroll")                                                          \
    for (int n = 0; n < NR; n++) bl[n] = *(const bf16x8*)(cp + 2 * AT + BT + boffs[n]); \
    _Pragma("unroll")                                                          \
    for (int m = 0; m < MR; m++)                                               \
      _Pragma("unroll")                                                        \
      for (int n = 0; n < NR; n++)                                             \
        acc[m][n] = __builtin_amdgcn_mfma_f32_16x16x32_bf16(ah[m], bh[n], acc[m][n], 0, 0, 0); \
    _Pragma("unroll")                                                          \
    for (int m = 0; m < MR; m++)                                               \
      _Pragma("unroll")                                                        \
      for (int n = 0; n < NR; n++)                                             \
        acc[m][n] = __builtin_amdgcn_mfma_f32_16x16x32_bf16(al[m], bh[n], acc[m][n], 0, 0, 0); \
    _Pragma("unroll")                                                          \
    for (int m = 0; m < MR; m++)                                               \
      _Pragma("unroll")                                                        \
      for (int n = 0; n < NR; n++)                                             \
        acc[m][n] = __builtin_amdgcn_mfma_f32_16x16x32_bf16(ah[m], bl[n], acc[m][n], 0, 0, 0); \
  }

  STAGE(lds, 0);
  STAGE(lds + BUF, 32);
  int ocur = 0, onext = BUF, ofar = 2 * BUF;
  for (int t = 0; t < nsteps; ++t) {
    if (t == nsteps - 1) wait_vm<0>(); else wait_vm<3>();
    __builtin_amdgcn_s_barrier();       // buf[t] staged for all waves; buf reads of t-1 done
    if (t + 2 < nsteps) STAGE(lds + ofar, (t + 2) << 5);  // stays in flight across barrier
    COMPUTE(lds + ocur);
    int tmp = ocur; ocur = onext; onext = ofar; ofar = tmp;
  }
#undef STAGE
#undef COMPUTE

#pragma unroll
  for (int m = 0; m < MR; m++) {
    const int row = m0 + wr * 32 + m * 16 + fq * 4;
#pragma unroll
    for (int n = 0; n < NR; n++) {
      const int col = n0 + wc * 32 + n * 16 + fr;
      float bcol = (ACT == 1) ? bias[col] : 0.f;
#pragma unroll
      for (int j = 0; j < 4; j++) {
        float v = acc[m][n][j];
        if (ACT == 1) v = softplus_f(v + bcol);
        C[(size_t)(row + j) * ldc + col] = v;
      }
    }
  }
}

// ---- 4-wave variant (BM=64, BN=64) for the small out-proj GEMM ----
template <int BM, int BN, int ACT>
__global__ __launch_bounds__(256) void gemm_mfma4(
    const ushort* __restrict__ Ahi, const ushort* __restrict__ Alo, int lda,
    const ushort* __restrict__ Bhi, const ushort* __restrict__ Blo, int ldb,
    const float* __restrict__ bias, float* __restrict__ C, int ldc, int K) {
  constexpr int AT = BM * 32;
  constexpr int BT = BN * 32;
  constexpr int BUF = 2 * AT + 2 * BT;
  constexpr int MR = BM / 32, NR = BN / 32;
  constexpr int LPS = (BM / 64) * 2 + (BN / 64) * 2;
  __shared__ __align__(16) ushort lds[3 * BUF];

  const int tid = threadIdx.x;
  const int lane = tid & 63;
  const int wave = tid >> 6;
  const int wr = wave >> 1, wc = wave & 1;

  const int nx = gridDim.x;
  const int nwg = nx * gridDim.y;
  int bid = blockIdx.y * nx + blockIdx.x;
  bid = (bid & 7) * (nwg >> 3) + (bid >> 3);
  const int m0 = (bid / nx) * BM;
  const int n0 = (bid % nx) * BN;

  const int r0 = tid >> 2;
  const int kg = (tid & 3) ^ ((r0 >> 1) & 3);
  const size_t aoff0 = (size_t)(m0 + r0) * lda + kg * 8;
  const size_t boff0 = (size_t)(n0 + r0) * ldb + kg * 8;

  const int fr = lane & 15, fq = lane >> 4;
  const int kswz = fq ^ ((fr >> 1) & 3);
  int aoffs[MR], boffs[NR];
#pragma unroll
  for (int m = 0; m < MR; m++) aoffs[m] = (wr * (BM / 2) + m * 16 + fr) * 32 + kswz * 8;
#pragma unroll
  for (int n = 0; n < NR; n++) boffs[n] = (wc * (BN / 2) + n * 16 + fr) * 32 + kswz * 8;

  f32x4 acc[MR][NR];
#pragma unroll
  for (int m = 0; m < MR; m++)
#pragma unroll
    for (int n = 0; n < NR; n++) acc[m][n] = (f32x4){0.f, 0.f, 0.f, 0.f};

  const int nsteps = K >> 5;

#define STAGE(base, kk)                                           \
  {                                                               \
    ushort* bp = (base);                                          \
    gload16(Ahi + aoff0 + (kk), bp + wave * 512);                 \
    gload16(Alo + aoff0 + (kk), bp + AT + wave * 512);            \
    gload16(Bhi + boff0 + (kk), bp + 2 * AT + wave * 512);        \
    gload16(Blo + boff0 + (kk), bp + 2 * AT + BT + wave * 512);   \
  }

#define COMPUTE(base)                                                          \
  {                                                                            \
    const ushort* cp = (base);                                                 \
    bf16x8 ah[MR], al[MR], bh[NR], bl[NR];                                     \
    _Pragma("unroll")                                                          \
    for (int m = 0; m < MR; m++) ah[m] = *(const bf16x8*)(cp + aoffs[m]);      \
    _Pragma("unroll")                                                          \
    for (int m = 0; m < MR; m++) al[m] = *(const bf16x8*)(cp + AT + aoffs[m]); \
    _Pragma("unroll")                                                          \
    for (int n = 0; n < NR; n++) bh[n] = *(const bf16x8*)(cp + 2 * AT + boffs[n]); \
    _Pragma("unroll")                                                          \
    for (int n = 0; n < NR; n++) bl[n] = *(const bf16x8*)(cp + 2 * AT + BT + boffs[n]); \
    _Pragma("unroll")                                                          \
    for (int m = 0; m < MR; m++)                                               \
      _Pragma("unroll")                                                        \
      for (int n = 0; n < NR; n++)                                             \
        acc[m][n] = __builtin_amdgcn_mfma_f32_16x16x32_bf16(ah[m], bh[n], acc[m][n], 0, 0, 0); \
    _Pragma("unroll")                                                          \
    for (int m = 0; m < MR; m++)                                               \
      _Pragma("unroll")                                                        \
      for (int n = 0; n < NR; n++)                                             \
        acc[m][n] = __builtin_amdgcn_mfma_f32_16x16x32_bf16(al[m], bh[n], acc[m][n], 0, 0, 0); \
    _Pragma("unroll")                                                          \
    for (int m = 0; m < MR; m++)                                               \
      _Pragma("unroll")                                                        \
      for (int n = 0; n < NR; n++)                                             \
        acc[m][n] = __builtin_amdgcn_mfma_f32_16x16x32_bf16(ah[m], bl[n], acc[m][n], 0, 0, 0); \
  }

  STAGE(lds, 0);
  STAGE(lds + BUF, 32);
  int ocur = 0, onext = BUF, ofar = 2 * BUF;
  for (int t = 0; t < nsteps; ++t) {
    if (t == nsteps - 1) wait_vm<0>(); else wait_vm<LPS>();
    __builtin_amdgcn_s_barrier();
    if (t + 2 < nsteps) STAGE(lds + ofar, (t + 2) << 5);
    COMPUTE(lds + ocur);
    int tmp = ocur; ocur = onext; onext = ofar; ofar = tmp;
  }
#undef STAGE
#undef COMPUTE

#pragma unroll
  for (int m = 0; m < MR; m++) {
    const int row = m0 + wr * (BM / 2) + m * 16 + fq * 4;
#pragma unroll
    for (int n = 0; n < NR; n++) {
      const int col = n0 + wc * (BN / 2) + n * 16 + fr;
      float bcol = (ACT == 1) ? bias[col] : 0.f;
#pragma unroll
      for (int j = 0; j < 4; j++) {
        float v = acc[m][n][j];
        if (ACT == 1) v = softplus_f(v + bcol);
        C[(size_t)(row + j) * ldc + col] = v;
      }
    }
  }
}

// depthwise causal conv (k=4) + SiLU; emits h fp32 and bf16 hi/lo split
__global__ __launch_bounds__(256) void conv_silu_kernel(
    const float* __restrict__ xz, const float* __restrict__ conv_w,
    const float* __restrict__ conv_b, float* __restrict__ h,
    ushort* __restrict__ h_hi, ushort* __restrict__ h_lo) {
  const int idx = blockIdx.x * 256 + threadIdx.x;
  const int c = idx & (DI - 1);
  const int r = idx >> 10;
  const int l = r & (L_SEQ - 1);
  const float w0 = conv_w[c * 4 + 0];
  const float w1 = conv_w[c * 4 + 1];
  const float w2 = conv_w[c * 4 + 2];
  const float w3 = conv_w[c * 4 + 3];
  const float* xp = xz + (size_t)r * (2 * DI) + c;
  float acc = conv_b[c];
  if (l >= 3) acc += xp[-3 * 2 * DI] * w0;
  if (l >= 2) acc += xp[-2 * 2 * DI] * w1;
  if (l >= 1) acc += xp[-1 * 2 * DI] * w2;
  acc += xp[0] * w3;
  const float hv = silu_f(acc);
  h[idx] = hv;
  const ushort hh = f2bf(hv);
  h_hi[idx] = hh;
  h_lo[idx] = f2bf(hv - bf2f(hh));
}

// Bmat[r][s] = dot(h[r][:], W_x[16+s][:])
__global__ __launch_bounds__(256) void xproj_kernel(
    const float* __restrict__ h, const float* __restrict__ W_x,
    float* __restrict__ Bm) {
  const int idx = blockIdx.x * 256 + threadIdx.x;
  const int s = idx & 15;
  const int r = idx >> 4;
  const float* hp = h + (size_t)r * DI;
  const float* wp = W_x + (size_t)(DS + s) * DI;
  float acc = 0.f;
  for (int k = 0; k < DI; k += 4) {
    float4 hv = *(const float4*)(hp + k);
    float4 wv = *(const float4*)(wp + k);
    acc += hv.x * wv.x + hv.y * wv.y + hv.z * wv.z + hv.w * wv.w;
  }
  Bm[idx] = acc;
}

// ---- chunked selective scan, channel-per-thread ----
__global__ __launch_bounds__(256) void scan_phase1(
    const float* __restrict__ delta, const float* __restrict__ h,
    const float* __restrict__ Bm, const float* __restrict__ A_log,
    float* __restrict__ aprod, float* __restrict__ blocal) {
  __shared__ float sB[CL * DS];  // 2KB
  const int tid = threadIdx.x;
  const int bid = blockIdx.x;
  const int cblk = bid & 3;
  const int chunk = (bid >> 2) & (NC - 1);
  const int b = bid >> 8;
  const int c = cblk * 256 + tid;
  const size_t row0 = (size_t)b * L_SEQ + chunk * CL;
  ((float2*)sB)[tid] = ((const float2*)(Bm + row0 * DS))[tid];
  __syncthreads();

  float Acs[DS], state[DS];
#pragma unroll
  for (int s = 0; s < DS; s += 4) {
    float4 al = *(const float4*)(A_log + (size_t)c * DS + s);
    Acs[s + 0] = -__expf(al.x);
    Acs[s + 1] = -__expf(al.y);
    Acs[s + 2] = -__expf(al.z);
    Acs[s + 3] = -__expf(al.w);
    state[s + 0] = 0.f; state[s + 1] = 0.f; state[s + 2] = 0.f; state[s + 3] = 0.f;
  }
  const float* dp = delta + row0 * DI + c;
  const float* hp = h + row0 * DI + c;
  float sdt = 0.f;
  for (int t = 0; t < CL; ++t) {
    const float dt = dp[(size_t)t * DI];
    const float ht = hp[(size_t)t * DI];
    const float dth = dt * ht;
    sdt += dt;
#pragma unroll
    for (int s = 0; s < DS; ++s)
      state[s] = __expf(dt * Acs[s]) * state[s] + dth * sB[t * DS + s];
  }
  const size_t o = (((size_t)b * NC + chunk) * DI + c) * DS;
#pragma unroll
  for (int s = 0; s < DS; s += 4) {
    *(float4*)(aprod + o + s) = make_float4(
        __expf(Acs[s] * sdt), __expf(Acs[s + 1] * sdt),
        __expf(Acs[s + 2] * sdt), __expf(Acs[s + 3] * sdt));
    *(float4*)(blocal + o + s) = make_float4(state[s], state[s + 1], state[s + 2], state[s + 3]);
  }
}

// serial scan over chunk summaries; writes sinit IN PLACE over aprod
__global__ __launch_bounds__(256) void scan_phase2(
    float* __restrict__ aprod, const float* __restrict__ blocal) {
  const int idx = blockIdx.x * 256 + threadIdx.x;  // NB*DI*DS = 32768
  const int b = idx >> 14;
  const int cs = idx & 16383;
  float st = 0.f;
  for (int ch = 0; ch < NC; ++ch) {
    const size_t o = (size_t)(b * NC + ch) * (DI * DS) + cs;
    const float a = aprod[o];
    const float bl = blocal[o];
    aprod[o] = st;   // sinit for this chunk
    st = a * st + bl;
  }
}

// phase3: rerun chunk with init state; fused gate + bf16 hi/lo split of y.
__global__ __launch_bounds__(256) void scan_phase3(
    const float* __restrict__ delta, const float* __restrict__ h,
    const float* __restrict__ Bm, const float* __restrict__ A_log,
    const float* __restrict__ sinit, float* __restrict__ xz,
    const float* __restrict__ Dp) {
  __shared__ float sB[CL * DS];
  const int tid = threadIdx.x;
  const int bid = blockIdx.x;
  const int cblk = bid & 3;
  const int chunk = (bid >> 2) & (NC - 1);
  const int b = bid >> 8;
  const int c = cblk * 256 + tid;
  const size_t row0 = (size_t)b * L_SEQ + chunk * CL;
  ((float2*)sB)[tid] = ((const float2*)(Bm + row0 * DS))[tid];
  __syncthreads();

  float Acs[DS], state[DS];
  const size_t o = (((size_t)b * NC + chunk) * DI + c) * DS;
#pragma unroll
  for (int s = 0; s < DS; s += 4) {
    float4 al = *(const float4*)(A_log + (size_t)c * DS + s);
    Acs[s + 0] = -__expf(al.x);
    Acs[s + 1] = -__expf(al.y);
    Acs[s + 2] = -__expf(al.z);
    Acs[s + 3] = -__expf(al.w);
    float4 sv = *(const float4*)(sinit + o + s);
    state[s + 0] = sv.x; state[s + 1] = sv.y; state[s + 2] = sv.z; state[s + 3] = sv.w;
  }
  const float* dp = delta + row0 * DI + c;
  const float* hp = h + row0 * DI + c;
  const float* zp = xz + row0 * (2 * DI) + DI + c;
  ushort* yrow = (ushort*)(xz + row0 * (2 * DI)) + c;  // row stride 4096 ushorts
  const float Dc = Dp[c];
  for (int t = 0; t < CL; ++t) {
    const float dt = dp[(size_t)t * DI];
    const float ht = hp[(size_t)t * DI];
    const float z = zp[(size_t)t * (2 * DI)];
    const float dth = dt * ht;
    float yv = 0.f;
#pragma unroll
    for (int s = 0; s < DS; ++s) {
      const float bt = sB[t * DS + s];
      state[s] = __expf(dt * Acs[s]) * state[s] + dth * bt;
      yv += state[s] * bt;
    }
    const float g = (yv + Dc * ht) * silu_f(z);
    const ushort gh = f2bf(g);
    yrow[(size_t)t * 4096] = gh;
    yrow[(size_t)t * 4096 + 1024] = f2bf(g - bf2f(gh));
  }
}

extern "C" void kernel_launch(void* const* d_in, const int* in_sizes, int n_in,
                              void* d_out, int out_size, void* d_ws, size_t ws_size,
                              hipStream_t stream) {
  const float* x      = (const float*)d_in[0];
  const float* W_in   = (const float*)d_in[1];
  const float* conv_w = (const float*)d_in[2];
  const float* conv_b = (const float*)d_in[3];
  const float* W_x    = (const float*)d_in[4];
  const float* W_dt   = (const float*)d_in[5];
  const float* b_dt   = (const float*)d_in[6];
  const float* A_log  = (const float*)d_in[7];
  const float* D_par  = (const float*)d_in[8];
  const float* W_out  = (const float*)d_in[9];
  float* out = (float*)d_out;

  const int rows = NB * L_SEQ;  // 4096

  // ws layout (floats) — ~92 MB total
  float* xz     = (float*)d_ws;                       // 8M floats
  float* h      = xz + (size_t)(8u << 20);            // 4M
  float* delta  = h + (size_t)(4u << 20);             // 4M
  float* Bm     = delta + (size_t)(4u << 20);         // 64K
  float* spare  = Bm + (size_t)(64u << 10);           // 1.5M
  float* wreg   = spare + (size_t)((3u << 20) / 2);   // 1.5M floats
  ushort* Wdt_hi  = (ushort*)wreg;
  ushort* Wdt_lo  = Wdt_hi + (size_t)(1u << 20);
  ushort* Wout_hi = Wdt_lo + (size_t)(1u << 20);
  ushort* Wout_lo = Wout_hi + (size_t)(512u << 10);
  float* xreg   = wreg + (size_t)((3u << 20) / 2);    // 4M floats region
  ushort* x_hi  = (ushort*)xreg;
  ushort* x_lo  = x_hi + (size_t)(2u << 20);
  ushort* Win_hi = x_lo + (size_t)(2u << 20);
  ushort* Win_lo = Win_hi + (size_t)(1u << 20);
  ushort* h_hi  = (ushort*)xreg;                      // overlay (x/W_in dead after GEMM1)
  ushort* h_lo  = h_hi + (size_t)(4u << 20);
  float* aprod  = xreg;                               // overlay (h_hi/h_lo dead after GEMM2)
  float* blocal = aprod + (size_t)(2u << 20);         // NB*NC*DI*DS = 2M floats each
  ushort* y_hi  = (ushort*)xz;                        // xi-cols overlay, lda 4096
  ushort* y_lo  = y_hi + 1024;

  // 0) bf16 hi/lo splits
  split_bf16<<<2048, 256, 0, stream>>>(x, x_hi, x_lo, rows * DM / 4);
  split_bf16<<<1024, 256, 0, stream>>>(W_in, Win_hi, Win_lo, 2 * DI * DM / 4);
  split_bf16<<<1024, 256, 0, stream>>>(W_dt, Wdt_hi, Wdt_lo, DI * DI / 4);
  split_bf16<<<512, 256, 0, stream>>>(W_out, Wout_hi, Wout_lo, DM * DI / 4);

  // 1) xz = x @ W_in^T   M=4096 N=2048 K=512   (8-wave, grid 1024)
  gemm_mfma8<0><<<dim3(32, 32), 512, 0, stream>>>(
      x_hi, x_lo, DM, Win_hi, Win_lo, DM, nullptr, xz, 2 * DI, DM);
  // 2) conv + silu -> h (+ hi/lo)
  conv_silu_kernel<<<(rows * DI) / 256, 256, 0, stream>>>(xz, conv_w, conv_b, h, h_hi, h_lo);
  // 3) delta = softplus(h @ W_dt^T + b_dt)   M=4096 N=1024 K=1024   (8-wave, grid 512)
  gemm_mfma8<1><<<dim3(16, 32), 512, 0, stream>>>(
      h_hi, h_lo, DI, Wdt_hi, Wdt_lo, DI, b_dt, delta, DI, DI);
  // 3b) Bmat
  xproj_kernel<<<(rows * DS) / 256, 256, 0, stream>>>(h, W_x, Bm);
  // 4) chunked scan
  scan_phase1<<<NB * NC * (DI / 256), 256, 0, stream>>>(delta, h, Bm, A_log, aprod, blocal);
  scan_phase2<<<(NB * DI * DS) / 256, 256, 0, stream>>>(aprod, blocal);
  scan_phase3<<<NB * NC * (DI / 256), 256, 0, stream>>>(delta, h, Bm, A_log, aprod, xz, D_par);
  // 5) out = y @ W_out^T   M=4096 N=512 K=1024   (4-wave 64x64, grid 512)
  gemm_mfma4<64, 64, 0><<<dim3(8, 64), 256, 0, stream>>>(
      y_hi, y_lo, 4096, Wout_hi, Wout_lo, DI, nullptr, out, DM, DI);
}